// Round 11
// baseline (1063.945 us; speedup 1.0000x reference)
//
#include <hip/hip_runtime.h>
#include <math.h>

#define B_ 8
#define L_ 2048
#define D_ 512
#define M_ 256
#define D2_ 1024
#define H_ 2048
#define N_ 16384          // B_*L_
#define EPS_ 1e-6f

typedef __attribute__((ext_vector_type(8))) short bf16x8;
typedef __attribute__((ext_vector_type(4))) float f32x4;
typedef unsigned short ushort_t;
typedef unsigned int uint_t;

// s_waitcnt immediates (gfx9 encoding): lgkmcnt=0xF(no wait), expcnt=7(no wait)
#define WAITCNT_VM8 0x0F78
#define WAITCNT_VM6 0x0F76
#define WAITCNT_VM4 0x0F74
#define WAITCNT_VM0 0x0F70

__device__ __forceinline__ ushort_t f2bf(float f) {
    uint_t u = __float_as_uint(f);
    u += 0x7FFFu + ((u >> 16) & 1u);        // round-to-nearest-even
    return (ushort_t)(u >> 16);
}
__device__ __forceinline__ float bf2f(ushort_t u) {
    return __uint_as_float(((uint_t)u) << 16);
}
__device__ __forceinline__ void gload_lds16(const void* g, void* l) {
    __builtin_amdgcn_global_load_lds(
        (const __attribute__((address_space(1))) void*)g,
        (__attribute__((address_space(3))) void*)l, 16, 0, 0);
}

// ---------------------------------------------------------------------------
// bf16 MFMA GEMM, 128x128 tile, BK=32, 2 LDS buffers (32 KiB), 256 thr.
// Used for narrow-grid / shallow-K GEMMs (pq, pkT, KVT', G, yo).
// K%64==0, rows/cols%128==0.
// ---------------------------------------------------------------------------
__global__ __launch_bounds__(256)
void gemm_mfma(const ushort_t* __restrict__ A, const ushort_t* __restrict__ Bm,
               void* __restrict__ Cp, int K, int lda, int ldb, int ldc,
               long long sA, long long sB, long long sC,
               int epi, float alpha, const float* __restrict__ aux,
               int auxStride, const float* __restrict__ bias, int obf)
{
    __shared__ ushort_t As[2][128 * 32];
    __shared__ ushort_t Bs[2][128 * 32];

    const int bz = blockIdx.z;
    A  += (long long)bz * sA;
    Bm += (long long)bz * sB;
    const int row0 = blockIdx.y * 128;
    const int col0 = blockIdx.x * 128;

    const int tid  = threadIdx.x;
    const int lane = tid & 63;
    const int wave = tid >> 6;
    const int wr = wave >> 1, wc = wave & 1;

    const int srow = tid >> 2;
    const int skol = (((tid & 3) ^ ((tid >> 3) & 3)) * 8);

    f32x4 acc[4][4];
    #pragma unroll
    for (int i = 0; i < 4; ++i)
        #pragma unroll
        for (int j = 0; j < 4; ++j)
            acc[i][j] = (f32x4){0.f, 0.f, 0.f, 0.f};

    const int fr = lane & 15;     // row/col within 16-tile
    const int fq = lane >> 4;     // k-quad
    const int koff = ((fq ^ ((fr >> 1) & 3))) * 8;

    const int nT = K >> 5;        // K-steps of 32; nT even (K%64==0)

    auto issue = [&](int t, ushort_t* Ad, ushort_t* Bd) {
        const int k0 = t << 5;
        gload_lds16(A + (long long)(row0 + srow) * lda + k0 + skol,
                    Ad + (wave * 16) * 32);
        gload_lds16(A + (long long)(row0 + 64 + srow) * lda + k0 + skol,
                    Ad + (64 + wave * 16) * 32);
        gload_lds16(Bm + (long long)(col0 + srow) * ldb + k0 + skol,
                    Bd + (wave * 16) * 32);
        gload_lds16(Bm + (long long)(col0 + 64 + srow) * ldb + k0 + skol,
                    Bd + (64 + wave * 16) * 32);
    };

    auto body = [&](int t, const ushort_t* Ac, const ushort_t* Bc,
                    ushort_t* An, ushort_t* Bn) {
        if (t + 1 < nT) {
            issue(t + 1, An, Bn);                      // buf^1: readers passed
            __builtin_amdgcn_s_waitcnt(WAITCNT_VM4);   //   body(t-1)'s barrier
        } else {
            __builtin_amdgcn_s_waitcnt(WAITCNT_VM0);
        }
        __builtin_amdgcn_s_barrier();

        bf16x8 a[4], b[4];
        #pragma unroll
        for (int i = 0; i < 4; ++i)
            a[i] = *(const bf16x8*)&Ac[(wr * 64 + i * 16 + fr) * 32 + koff];
        #pragma unroll
        for (int j = 0; j < 4; ++j)
            b[j] = *(const bf16x8*)&Bc[(wc * 64 + j * 16 + fr) * 32 + koff];
        #pragma unroll
        for (int i = 0; i < 4; ++i)
            #pragma unroll
            for (int j = 0; j < 4; ++j)
                acc[i][j] = __builtin_amdgcn_mfma_f32_16x16x32_bf16(
                    a[i], b[j], acc[i][j], 0, 0, 0);
        __builtin_amdgcn_s_barrier();
    };

    issue(0, As[0], Bs[0]);
    for (int t = 0; t < nT; t += 2) {
        body(t,     As[0], Bs[0], As[1], Bs[1]);
        body(t + 1, As[1], Bs[1], As[0], Bs[0]);
    }

    // epilogue: C/D layout col=lane&15, row=(lane>>4)*4+reg
    const int gr0 = row0 + wr * 64;
    const int gc0 = col0 + wc * 64;
    #pragma unroll
    for (int i = 0; i < 4; ++i) {
        #pragma unroll
        for (int r = 0; r < 4; ++r) {
            const int row = gr0 + i * 16 + fq * 4 + r;
            float raux = 0.f;
            if (epi == 1 || epi == 2) raux = aux[(long long)bz * auxStride + row];
            #pragma unroll
            for (int j = 0; j < 4; ++j) {
                const int col = gc0 + j * 16 + fr;
                float v = acc[i][j][r];
                if (epi == 0)      v *= alpha;
                else if (epi == 1) v -= 0.5f * raux;
                else if (epi == 2) v = v / (raux + EPS_);
                else if (epi == 5) v -= 0.5f * aux[(long long)bz * auxStride + col];
                else if (epi == 3) { v += bias[col]; v = v > 0.f ? v : 0.f; }
                else if (epi == 4) v += bias[col];
                const long long off = (long long)bz * sC + (long long)row * ldc + col;
                if (obf) ((ushort_t*)Cp)[off] = f2bf(v);
                else     ((float*)Cp)[off] = v;
            }
        }
    }
}

// ---------------------------------------------------------------------------
// 256x256 8-phase bf16 GEMM (round-2 proven schedule, no XCD swizzle).
// BK=64, 512 thr = 8 waves (2M x 4N), LDS 128 KiB 2-dbuf.
// Stage placement per body(t) (liveness-verified, passed rounds 2-10):
//   P0: (t+1, Ah3) -> buf^1 ; P2: (t+2, Bh1) ; P3: (t+2, Bh2), (t+2, Ah0)
// vmcnt(6) once per K-tile boundary.
// Split-K (ksplit>1): blockIdx.z = batch*ksplit + kz; epilogue atomicAdds
// fp32 into pre-seeded C (seed_c). Requires fp32 out.
// Requires rows%256==0, cols%256==0, (K/ksplit)%128==0, K>=512 (pipeline:
// the 2-tile-deep prologue needs nT>=8 to amortize; K=256 never fills it).
// ---------------------------------------------------------------------------
__global__ __launch_bounds__(512, 2)
void gemm256(const ushort_t* __restrict__ A, const ushort_t* __restrict__ Bm,
             void* __restrict__ Cp, int K, int lda, int ldb, int ldc,
             long long sA, long long sB, long long sC,
             int epi, float alpha, const float* __restrict__ aux,
             int auxStride, const float* __restrict__ bias, int obf,
             int ksplit)
{
    __shared__ ushort_t As[2][256 * 64];
    __shared__ ushort_t Bs[2][256 * 64];

    const int bzf = blockIdx.z;
    const int bz = bzf / ksplit;        // batch
    const int kz = bzf - bz * ksplit;   // K-split index
    const int Kh = K / ksplit;

    A  += (long long)bz * sA + (long long)kz * Kh;
    Bm += (long long)bz * sB + (long long)kz * Kh;
    const int row0 = blockIdx.y * 256;
    const int col0 = blockIdx.x * 256;

    const int tid  = threadIdx.x;
    const int lane = tid & 63;
    const int wave = tid >> 6;          // 0..7
    const int wr   = wave >> 2;         // 0..1  (M half)
    const int wcn  = wave & 3;          // 0..3  (N quarter)

    // staging: thread covers (row rloc, 16B chunk tid&7); src pre-swizzled
    const int rloc  = tid >> 3;                         // 0..63
    const int csrc8 = (((tid & 7) ^ (rloc & 7)) << 3);  // element offset

    // fragment read: lane(fq,fr); physical chunk = logical ^ (fr&7)
    const int fr = lane & 15;
    const int fq = lane >> 4;
    const int sw = fr & 7;
    const int c0off = ((fq ^ sw) << 3);          // k1=0
    const int c1off = (((4 | fq) ^ sw) << 3);    // k1=1

    const int nT = Kh >> 6;             // K-tiles of 64; nT even (Kh%128==0)

    f32x4 acc[8][4];
    #pragma unroll
    for (int i = 0; i < 8; ++i)
        #pragma unroll
        for (int j = 0; j < 4; ++j)
            acc[i][j] = (f32x4){0.f, 0.f, 0.f, 0.f};

    bf16x8 a[4][2];   // current M-half fragments
    bf16x8 b[4][2];   // all 4 N fragments (b[0..1] live P0->P3)

    auto stage = [&](int bufS, int tS, int half) {
        const int k0 = tS << 6;
        const int rh = (half >= 2) ? 1 : 0;       // h2(B1)/h3(A1) -> upper 128
        const bool isA = (half == 0 || half == 3);
        const ushort_t* g = isA
            ? A  + (long long)(row0 + rh * 128 + rloc) * lda + k0 + csrc8
            : Bm + (long long)(col0 + rh * 128 + rloc) * ldb + k0 + csrc8;
        const long long gstep = 64LL * (isA ? lda : ldb);
        ushort_t* l = (isA ? &As[bufS][0] : &Bs[bufS][0])
                      + (rh * 128 + wave * 8) * 64;
        gload_lds16(g, l);                 // rows [base, base+64)
        gload_lds16(g + gstep, l + 64 * 64);
    };

    auto ldsA = [&](int buf, int mh, int i, int koff) -> bf16x8 {
        return *(const bf16x8*)
            &As[buf][(wr * 128 + mh * 64 + i * 16 + fr) * 64 + koff];
    };
    auto ldsB = [&](int buf, int j, int koff) -> bf16x8 {
        return *(const bf16x8*)
            &Bs[buf][(wcn * 64 + j * 16 + fr) * 64 + koff];
    };

    // prologue: tile0 all 4 halves + tile1 {Ah0, Bh1, Bh2} = 7 half-stages
    // (14 loads); vmcnt(6) -> tile 0 fully landed, tile 1 trio in flight.
    stage(0, 0, 0); stage(0, 0, 1); stage(0, 0, 2); stage(0, 0, 3);
    stage(1, 1, 0); stage(1, 1, 1); stage(1, 1, 2);
    __builtin_amdgcn_s_waitcnt(WAITCNT_VM6);
    __builtin_amdgcn_s_barrier();

    auto tile_body = [&](int t, int buf) {
        // ---- P0: ds a(mh0) + b(n01); stage (t+1, Ah3)->buf^1; mfma Q(0,n01)
        #pragma unroll
        for (int i = 0; i < 4; ++i) {
            a[i][0] = ldsA(buf, 0, i, c0off);
            a[i][1] = ldsA(buf, 0, i, c1off);
        }
        #pragma unroll
        for (int j = 0; j < 2; ++j) {
            b[j][0] = ldsB(buf, j, c0off);
            b[j][1] = ldsB(buf, j, c1off);
        }
        if (t + 1 < nT) stage(buf ^ 1, t + 1, 3);
        __builtin_amdgcn_s_barrier();
        asm volatile("s_waitcnt lgkmcnt(0)" ::: "memory");
        __builtin_amdgcn_s_setprio(1);
        #pragma unroll
        for (int i = 0; i < 4; ++i)
            #pragma unroll
            for (int j = 0; j < 2; ++j) {
                acc[i][j] = __builtin_amdgcn_mfma_f32_16x16x32_bf16(
                    a[i][0], b[j][0], acc[i][j], 0, 0, 0);
                acc[i][j] = __builtin_amdgcn_mfma_f32_16x16x32_bf16(
                    a[i][1], b[j][1], acc[i][j], 0, 0, 0);
            }
        __builtin_amdgcn_s_setprio(0);
        __builtin_amdgcn_s_barrier();

        // ---- P1: ds b(n23); NO stage (A[buf] live until P2); mfma Q(0,n23)
        #pragma unroll
        for (int j = 2; j < 4; ++j) {
            b[j][0] = ldsB(buf, j, c0off);
            b[j][1] = ldsB(buf, j, c1off);
        }
        __builtin_amdgcn_s_barrier();
        asm volatile("s_waitcnt lgkmcnt(0)" ::: "memory");
        __builtin_amdgcn_s_setprio(1);
        #pragma unroll
        for (int i = 0; i < 4; ++i)
            #pragma unroll
            for (int j = 2; j < 4; ++j) {
                acc[i][j] = __builtin_amdgcn_mfma_f32_16x16x32_bf16(
                    a[i][0], b[j][0], acc[i][j], 0, 0, 0);
                acc[i][j] = __builtin_amdgcn_mfma_f32_16x16x32_bf16(
                    a[i][1], b[j][1], acc[i][j], 0, 0, 0);
            }
        __builtin_amdgcn_s_setprio(0);
        __builtin_amdgcn_s_barrier();

        // ---- P2: ds a(mh1); stage (t+2, Bh1); mfma Q(1, n23)
        #pragma unroll
        for (int i = 0; i < 4; ++i) {
            a[i][0] = ldsA(buf, 1, i, c0off);
            a[i][1] = ldsA(buf, 1, i, c1off);
        }
        if (t + 2 < nT) stage(buf, t + 2, 1);
        __builtin_amdgcn_s_barrier();
        asm volatile("s_waitcnt lgkmcnt(0)" ::: "memory");
        __builtin_amdgcn_s_setprio(1);
        #pragma unroll
        for (int i = 0; i < 4; ++i)
            #pragma unroll
            for (int j = 2; j < 4; ++j) {
                acc[4 + i][j] = __builtin_amdgcn_mfma_f32_16x16x32_bf16(
                    a[i][0], b[j][0], acc[4 + i][j], 0, 0, 0);
                acc[4 + i][j] = __builtin_amdgcn_mfma_f32_16x16x32_bf16(
                    a[i][1], b[j][1], acc[4 + i][j], 0, 0, 0);
            }
        __builtin_amdgcn_s_setprio(0);
        __builtin_amdgcn_s_barrier();

        // ---- P3: no ds reads; stage (t+2, Bh2), (t+2, Ah0); mfma Q(1, n01);
        //          tile-boundary counted vmcnt.
        if (t + 2 < nT) { stage(buf, t + 2, 2); stage(buf, t + 2, 0); }
        __builtin_amdgcn_s_barrier();
        asm volatile("s_waitcnt lgkmcnt(0)" ::: "memory");
        __builtin_amdgcn_s_setprio(1);
        #pragma unroll
        for (int i = 0; i < 4; ++i)
            #pragma unroll
            for (int j = 0; j < 2; ++j) {
                acc[4 + i][j] = __builtin_amdgcn_mfma_f32_16x16x32_bf16(
                    a[i][0], b[j][0], acc[4 + i][j], 0, 0, 0);
                acc[4 + i][j] = __builtin_amdgcn_mfma_f32_16x16x32_bf16(
                    a[i][1], b[j][1], acc[4 + i][j], 0, 0, 0);
            }
        __builtin_amdgcn_s_setprio(0);
        if (t + 2 < nT)      __builtin_amdgcn_s_waitcnt(WAITCNT_VM6);
        else if (t + 1 < nT) __builtin_amdgcn_s_waitcnt(WAITCNT_VM0);
        __builtin_amdgcn_s_barrier();
    };

    for (int t = 0; t < nT; t += 2) {
        tile_body(t, 0);
        tile_body(t + 1, 1);
    }

    // epilogue: C/D layout col=lane&15, row=(lane>>4)*4+reg
    const int gr0 = row0 + wr * 128;
    const int gc0 = col0 + wcn * 64;
    #pragma unroll
    for (int i = 0; i < 8; ++i) {
        #pragma unroll
        for (int r = 0; r < 4; ++r) {
            const int row = gr0 + i * 16 + fq * 4 + r;
            float raux = 0.f;
            if (epi == 1 || epi == 2) raux = aux[(long long)bz * auxStride + row];
            #pragma unroll
            for (int j = 0; j < 4; ++j) {
                const int col = gc0 + j * 16 + fr;
                float v = acc[i][j][r];
                const long long off = (long long)bz * sC + (long long)row * ldc + col;
                if (ksplit > 1) {
                    // C pre-seeded (bias or zero); fp32 accumulate
                    atomicAdd((float*)Cp + off, v * alpha);
                    continue;
                }
                if (epi == 0)      v *= alpha;
                else if (epi == 1) v -= 0.5f * raux;
                else if (epi == 2) v = v / (raux + EPS_);
                else if (epi == 5) v -= 0.5f * aux[(long long)bz * auxStride + col];
                else if (epi == 3) { v += bias[col]; v = v > 0.f ? v : 0.f; }
                else if (epi == 4) v += bias[col];
                if (obf) ((ushort_t*)Cp)[off] = f2bf(v);
                else     ((float*)Cp)[off] = v;
            }
        }
    }
}

// seed C rows with bias[col] (bias!=null) or zero, ldc = 1024
__global__ __launch_bounds__(256)
void seed_c(const float* __restrict__ bias, float* __restrict__ C)
{
    const long long t = (long long)blockIdx.x * 256 + threadIdx.x;
    C[t] = bias ? bias[(int)(t & (D2_ - 1))] : 0.f;
}

// ---------- build / convert kernels ----------------------------------------

// 1024x1024 fp32 W -> bf16 W^T  (out[n][k] = W[k][n])
__global__ __launch_bounds__(256)
void transpose_cvt_sq(const float* __restrict__ W, ushort_t* __restrict__ out)
{
    __shared__ float S[32][33];
    const int tx = threadIdx.x & 31, ty = threadIdx.x >> 5;
    const int n0 = blockIdx.x * 32, k0 = blockIdx.y * 32;
    #pragma unroll
    for (int r = 0; r < 4; ++r)
        S[ty + 8 * r][tx] = W[(long long)(k0 + ty + 8 * r) * 1024 + n0 + tx];
    __syncthreads();
    #pragma unroll
    for (int r = 0; r < 4; ++r)
        out[(long long)(n0 + ty + 8 * r) * 1024 + k0 + tx] = f2bf(S[tx][ty + 8 * r]);
}

// wc1T (4096 x 1024): out[j][i] of combined [[W1r,W1i],[-W1i,W1r]]
__global__ __launch_bounds__(256)
void build_wc1T(const float* __restrict__ W1r, const float* __restrict__ W1i,
                ushort_t* __restrict__ out)
{
    __shared__ float S[32][33];
    const int tx = threadIdx.x & 31, ty = threadIdx.x >> 5;
    const int i0 = blockIdx.x * 32, j0 = blockIdx.y * 32;
    #pragma unroll
    for (int r = 0; r < 4; ++r) {
        const int i = i0 + ty + 8 * r, j = j0 + tx;
        float v;
        if (j < H_) v = (i < D_) ? W1r[(long long)i * H_ + j]
                                 : -W1i[(long long)(i - D_) * H_ + j];
        else {
            const int jj = j - H_;
            v = (i < D_) ? W1i[(long long)i * H_ + jj]
                         : W1r[(long long)(i - D_) * H_ + jj];
        }
        S[tx][ty + 8 * r] = v;
    }
    __syncthreads();
    #pragma unroll
    for (int r = 0; r < 4; ++r)
        out[(long long)(j0 + ty + 8 * r) * 1024 + i0 + tx] = f2bf(S[ty + 8 * r][tx]);
}

// wc2T (1024 x 4096): out[j][i] of combined [[W2r,W2i],[-W2i,W2r]]
__global__ __launch_bounds__(256)
void build_wc2T(const float* __restrict__ W2r, const float* __restrict__ W2i,
                ushort_t* __restrict__ out)
{
    __shared__ float S[32][33];
    const int tx = threadIdx.x & 31, ty = threadIdx.x >> 5;
    const int i0 = blockIdx.x * 32, j0 = blockIdx.y * 32;
    #pragma unroll
    for (int r = 0; r < 4; ++r) {
        const int i = i0 + ty + 8 * r, j = j0 + tx;
        float v;
        if (i < H_) v = (j < D_) ? W2r[(long long)i * D_ + j]
                                 : W2i[(long long)i * D_ + (j - D_)];
        else {
            const int ii = i - H_;
            v = (j < D_) ? -W2i[(long long)ii * D_ + j]
                         : W2r[(long long)ii * D_ + (j - D_)];
        }
        S[tx][ty + 8 * r] = v;
    }
    __syncthreads();
    #pragma unroll
    for (int r = 0; r < 4; ++r)
        out[(long long)(j0 + ty + 8 * r) * 4096 + i0 + tx] = f2bf(S[ty + 8 * r][tx]);
}

__global__ __launch_bounds__(256)
void build_bias(const float* __restrict__ b1r, const float* __restrict__ b1i,
                const float* __restrict__ b2r, const float* __restrict__ b2i,
                float* __restrict__ bc1, float* __restrict__ bc2)
{
    const int t = blockIdx.x * 256 + threadIdx.x;   // grid 16 -> t < 4096
    bc1[t] = (t < H_) ? b1r[t] : b1i[t - H_];
    if (t < D2_) bc2[t] = (t < D_) ? b2r[t] : b2i[t - D_];
}

__global__ __launch_bounds__(256)
void cvt_Wf(const float* __restrict__ Wf, ushort_t* __restrict__ out)
{
    const int t = blockIdx.x * 256 + threadIdx.x;   // 262144
    out[t] = f2bf(Wf[t]);
}

// x_bf (N x D2) = bf16(concat(zr, zi))
__global__ __launch_bounds__(256)
void cvt_x(const float* __restrict__ zr, const float* __restrict__ zi,
           ushort_t* __restrict__ x)
{
    long long t = (long long)blockIdx.x * 256 + threadIdx.x;  // N*D2/4
    long long n = t >> 8;
    int j4 = (int)(t & 255) << 2;
    float4 v;
    if (j4 < D_) v = *(const float4*)(zr + n * D_ + j4);
    else         v = *(const float4*)(zi + n * D_ + (j4 - D_));
    uint2 o;
    o.x = (uint_t)f2bf(v.x) | ((uint_t)f2bf(v.y) << 16);
    o.y = (uint_t)f2bf(v.z) | ((uint_t)f2bf(v.w) << 16);
    *(uint2*)(x + n * D2_ + j4) = o;
}

// ssq[n] = sum_k bf2f(A[n,k])^2, row len 1024, one wave per row
// (k-side only: phi_k uses a GLOBAL max so the row-shift matters; the q-side
//  row-shift cancels under per-row max-subtraction and is not computed.)
__global__ __launch_bounds__(256)
void rowsumsq_bf(const ushort_t* __restrict__ A, float* __restrict__ out)
{
    const int wid = threadIdx.x >> 6, lane = threadIdx.x & 63;
    const long long row = (long long)blockIdx.x * 4 + wid;
    const ushort_t* a = A + row * D2_;
    float s = 0.f;
    #pragma unroll
    for (int h = 0; h < 2; ++h) {
        uint4 u = *(const uint4*)(a + h * 512 + lane * 8);
        const uint_t w[4] = {u.x, u.y, u.z, u.w};
        #pragma unroll
        for (int p = 0; p < 4; ++p) {
            float lo = bf2f((ushort_t)(w[p] & 0xffff));
            float hi = bf2f((ushort_t)(w[p] >> 16));
            s += lo * lo + hi * hi;
        }
    }
    #pragma unroll
    for (int off = 32; off; off >>= 1) s += __shfl_down(s, off, 64);
    if (lane == 0) out[row] = s;
}

// phi_q: per-row max-subtract + exp over M=256, pq fp32 -> bf16 out
__global__ __launch_bounds__(256)
void phi_rowmax_exp(const float* __restrict__ P, ushort_t* __restrict__ out)
{
    const long long row = blockIdx.x;
    const int t = threadIdx.x;
    const float v = P[row * M_ + t];
    float m = v;
    #pragma unroll
    for (int off = 32; off; off >>= 1) m = fmaxf(m, __shfl_down(m, off, 64));
    __shared__ float sm[4];
    const int wid = t >> 6, lane = t & 63;
    if (lane == 0) sm[wid] = m;
    __syncthreads();
    const float mm = fmaxf(fmaxf(sm[0], sm[1]), fmaxf(sm[2], sm[3]));
    out[row * M_ + t] = f2bf(expf(v - mm) * 0.0625f);
}

__global__ __launch_bounds__(256)
void gmax1(const float* __restrict__ P, float* __restrict__ part, int n)
{
    float m = -3.4e38f;
    for (long long i = (long long)blockIdx.x * 256 + threadIdx.x; i < n;
         i += (long long)gridDim.x * 256)
        m = fmaxf(m, P[i]);
    #pragma unroll
    for (int off = 32; off; off >>= 1) m = fmaxf(m, __shfl_down(m, off, 64));
    __shared__ float sm[4];
    const int wid = threadIdx.x >> 6, lane = threadIdx.x & 63;
    if (lane == 0) sm[wid] = m;
    __syncthreads();
    if (threadIdx.x == 0)
        part[blockIdx.x] = fmaxf(fmaxf(sm[0], sm[1]), fmaxf(sm[2], sm[3]));
}

__global__ __launch_bounds__(256)
void gmax2(float* __restrict__ red)
{
    float m = -3.4e38f;
    for (int i = threadIdx.x; i < 1024; i += 256) m = fmaxf(m, red[256 + i]);
    #pragma unroll
    for (int off = 32; off; off >>= 1) m = fmaxf(m, __shfl_down(m, off, 64));
    __shared__ float sm[4];
    const int wid = threadIdx.x >> 6, lane = threadIdx.x & 63;
    if (lane == 0) sm[wid] = m;
    __syncthreads();
    if (threadIdx.x == 0) red[0] = fmaxf(fmaxf(sm[0], sm[1]), fmaxf(sm[2], sm[3]));
}

// phi_kT = bf16(exp(pkT - gmax)/16)
__global__ __launch_bounds__(256)
void phikT_exp(const float* __restrict__ P, const float* __restrict__ red,
               ushort_t* __restrict__ out)
{
    const long long i = (long long)blockIdx.x * 256 + threadIdx.x;
    out[i] = f2bf(expf(P[i] - red[0]) * 0.0625f);
}

// ksum[b,m] = sum_l phi_kT[m, b*L+l]; one block per (b,m)
__global__ __launch_bounds__(256)
void ksum_k(const ushort_t* __restrict__ phikT, float* __restrict__ ks)
{
    const int b = blockIdx.x >> 8, m = blockIdx.x & 255;
    const ushort_t* p = phikT + (long long)m * N_ + b * L_;
    uint4 u = *(const uint4*)(p + threadIdx.x * 8);
    const uint_t w[4] = {u.x, u.y, u.z, u.w};
    float s = 0.f;
    #pragma unroll
    for (int q = 0; q < 4; ++q)
        s += bf2f((ushort_t)(w[q] & 0xffff)) + bf2f((ushort_t)(w[q] >> 16));
    #pragma unroll
    for (int off = 32; off; off >>= 1) s += __shfl_down(s, off, 64);
    __shared__ float sm[4];
    const int wid = threadIdx.x >> 6, lane = threadIdx.x & 63;
    if (lane == 0) sm[wid] = s;
    __syncthreads();
    if (threadIdx.x == 0)
        ks[blockIdx.x] = sm[0] + sm[1] + sm[2] + sm[3];
}

// den[n] = sum_m phi_q_bf[n,m]*ksum[b,m]; one wave per row
__global__ __launch_bounds__(256)
void den_k(const ushort_t* __restrict__ phiq, const float* __restrict__ ks,
           float* __restrict__ den)
{
    const int wid = threadIdx.x >> 6, lane = threadIdx.x & 63;
    const long long n = (long long)blockIdx.x * 4 + wid;
    const int b = (int)(n >> 11);
    uint2 u = *(const uint2*)(phiq + n * M_ + lane * 4);
    float4 kk = *(const float4*)(ks + b * M_ + lane * 4);
    float s = bf2f((ushort_t)(u.x & 0xffff)) * kk.x
            + bf2f((ushort_t)(u.x >> 16)) * kk.y
            + bf2f((ushort_t)(u.y & 0xffff)) * kk.z
            + bf2f((ushort_t)(u.y >> 16)) * kk.w;
    #pragma unroll
    for (int off = 32; off; off >>= 1) s += __shfl_down(s, off, 64);
    if (lane == 0) den[n] = s;
}

// zst_bf = bf16(modrelu(z + yo)); yo is bf16 (N x D2), full-N launch
__global__ __launch_bounds__(256)
void modrelu_attn(const float* __restrict__ zr, const float* __restrict__ zi,
                  const ushort_t* __restrict__ yo, const float* __restrict__ b_attn,
                  ushort_t* __restrict__ zst)
{
    const long long t = (long long)blockIdx.x * 256 + threadIdx.x;
    const long long n = t >> 9; const int d = (int)(t & 511);
    const float ar = zr[t] + bf2f(yo[n * D2_ + d]);
    const float ai = zi[t] + bf2f(yo[n * D2_ + D_ + d]);
    const float mag = sqrtf(ar * ar + ai * ai + EPS_);
    const float s = fmaxf(mag + b_attn[d], 0.f) / mag;
    zst[n * D2_ + d]      = f2bf(ar * s);
    zst[n * D2_ + D_ + d] = f2bf(ai * s);
}

// out chunk = modrelu(zst + f) interleaved; zst(bf16)/f/out pre-offset
__global__ __launch_bounds__(256)
void modrelu_out(const ushort_t* __restrict__ zst, const float* __restrict__ f,
                 const float* __restrict__ b_ffn, float* __restrict__ out)
{
    const long long t = (long long)blockIdx.x * 256 + threadIdx.x;
    const long long n = t >> 9; const int d = (int)(t & 511);
    const float ar = bf2f(zst[n * D2_ + d])      + f[n * D2_ + d];
    const float ai = bf2f(zst[n * D2_ + D_ + d]) + f[n * D2_ + D_ + d];
    const float mag = sqrtf(ar * ar + ai * ai + EPS_);
    const float s = fmaxf(mag + b_ffn[d], 0.f) / mag;
    out[t * 2]     = ar * s;
    out[t * 2 + 1] = ai * s;
}

extern "C" void kernel_launch(void* const* d_in, const int* in_sizes, int n_in,
                              void* d_out, int out_size, void* d_ws, size_t ws_size,
                              hipStream_t stream)
{
    const float* zr    = (const float*)d_in[0];
    const float* zi    = (const float*)d_in[1];
    const float* Wq    = (const float*)d_in[2];
    const float* Wk    = (const float*)d_in[3];
    const float* Wv    = (const float*)d_in[4];
    const float* Wo    = (const float*)d_in[5];
    const float* Wf    = (const float*)d_in[6];
    const float* b_attn= (const float*)d_in[7];
    const float* W1r   = (const float*)d_in[8];
    const float* W1i   = (const float*)d_in[9];
    const float* b1r   = (const float*)d_in[10];
    const float* b1i   = (const float*)d_in[11];
    const float* W2r   = (const float*)d_in[12];
    const float* W2i   = (const float*)d_in[13];
    const float* b2r   = (const float*)d_in[14];
    const float* b2i   = (const float*)d_in[15];
    const float* b_ffn = (const float*)d_in[16];

    char* w = (char*)d_ws;
    // Attention-phase layout (~124 MB):
    ushort_t* Xbf = (ushort_t*)(w + 0LL);          // x_bf -> zst_bf (33.55 MB)
    ushort_t* A1  = (ushort_t*)(w + 33554432LL);   // q/k -> vT (33.55 MB)
    float*    P   = (float*)   (w + 67108864LL);   // pq/pkT -> yo_bf16 (16.8)
    ushort_t* WqT = (ushort_t*)(w + 83886080LL);   // after P (dead then)
    ushort_t* WkT = (ushort_t*)(w + 85983232LL);
    ushort_t* WvT = (ushort_t*)(w + 88080384LL);
    ushort_t* Wfb = (ushort_t*)(w + 90177536LL);
    ushort_t* F1  = (ushort_t*)(w + 100663296LL);  // phi_q_bf -> wc1T (8.39 MB)
    ushort_t* F2  = (ushort_t*)(w + 109051904LL);  // phi_kT -> G -> wc2T (8.39)
    ushort_t* WoT = (ushort_t*)(w + 117440512LL);  // 2 MB
    ushort_t* KVT = (ushort_t*)(w + 119537664LL);  // KVT' (8,256,1024) bf16, 4MB
    float* ssqk = (float*)(w + 123797504LL);
    float* den  = (float*)(w + 123863040LL);
    float* ksum = (float*)(w + 123928576LL);
    float* red  = (float*)(w + 123936768LL);

    // FFN-phase layout, gated on ws_size:
    const bool big = ws_size >= 152000000ULL;
    const int  RCH = big ? 8192 : 4096;
    ushort_t* Hb = (ushort_t*)(w + 33554432LL);
    float* Fb  = big ? (float*)(w + 117440512LL) : (float*)(w + 67108864LL);
    float* bc1 = big ? (float*)(w + 150994944LL) : (float*)(w + 123944960LL);
    float* bc2 = big ? (float*)(w + 151011328LL) : (float*)(w + 123961344LL);

    const float scl = 0.1767766952966369f;  // D2^-0.25
    dim3 blk(256);

    // Route: 256x256 8-phase kernel when the grid is wide enough (>=128 wgs)
    // AND K>=512 (its 2-tile-deep pipeline needs nT>=8; yo's K=256 gives
    // nT=4 -- the prologue stages 7/8 of the whole K-range and drains).
    // Else the 128x128 2-buffer kernel.
    auto GM = [&](const ushort_t* A, const ushort_t* Bm, void* C,
                  int rows, int cols, int K, int lda, int ldb, int ldc,
                  long long sA, long long sB, long long sC, int nb,
                  int epi, float alpha, const float* aux, int auxStride,
                  const float* bias, int obf) {
        const long long wg256 = (long long)(cols >> 8) * (rows >> 8) * nb;
        if ((rows & 255) == 0 && (cols & 255) == 0 && (K & 127) == 0 &&
            K >= 512 && wg256 >= 128) {
            dim3 grid(cols / 256, rows / 256, nb);
            gemm256<<<grid, dim3(512), 0, stream>>>(A, Bm, C, K, lda, ldb, ldc,
                                                    sA, sB, sC, epi, alpha, aux,
                                                    auxStride, bias, obf, 1);
        } else {
            dim3 grid(cols / 128, rows / 128, nb);
            gemm_mfma<<<grid, blk, 0, stream>>>(A, Bm, C, K, lda, ldb, ldc,
                                                sA, sB, sC, epi, alpha, aux,
                                                auxStride, bias, obf);
        }
    };

    // ---- one-time weight prep + input convert ----
    transpose_cvt_sq<<<dim3(32, 32), blk, 0, stream>>>(Wq, WqT);
    transpose_cvt_sq<<<dim3(32, 32), blk, 0, stream>>>(Wk, WkT);
    transpose_cvt_sq<<<dim3(32, 32), blk, 0, stream>>>(Wv, WvT);
    transpose_cvt_sq<<<dim3(32, 32), blk, 0, stream>>>(Wo, WoT);
    cvt_Wf<<<1024, blk, 0, stream>>>(Wf, Wfb);
    build_bias<<<16, blk, 0, stream>>>(b1r, b1i, b2r, b2i, bc1, bc2);
    cvt_x<<<N_ * (D2_ / 4) / 256, blk, 0, stream>>>(zr, zi, Xbf);

    // ---- q phase: q_bf = x@WqT*scl; pq = q@Wf^T (the -0.5*ssqq row-shift
    //      cancels under per-row max-subtraction -- not computed); phi_q ----
    GM(Xbf, WqT, A1, N_, D2_, D2_, D2_, D2_, D2_, 0, 0, 0, 1, 0, scl, nullptr, 0, nullptr, 1);
    GM(A1, Wfb, P, N_, M_, D2_, D2_, D2_, M_, 0, 0, 0, 1, 0, 1.f, nullptr, 0, nullptr, 0);
    phi_rowmax_exp<<<N_, blk, 0, stream>>>(P, F1);

    // ---- k phase: k_bf; ssqk; pkT = Wf@k^T - 0.5ssqk[col]; phi_kT ----
    GM(Xbf, WkT, A1, N_, D2_, D2_, D2_, D2_, D2_, 0, 0, 0, 1, 0, scl, nullptr, 0, nullptr, 1);
    rowsumsq_bf<<<N_ / 4, blk, 0, stream>>>(A1, ssqk);
    GM(Wfb, A1, P, M_, N_, D2_, D2_, D2_, N_, 0, 0, 0, 1, 5, 1.f, ssqk, 0, nullptr, 0);
    gmax1<<<1024, blk, 0, stream>>>(P, red + 256, M_ * N_);
    gmax2<<<1, blk, 0, stream>>>(red);
    phikT_exp<<<M_ * N_ / 256, blk, 0, stream>>>(P, red, F2);

    // ---- vT = Wv^T @ x^T (1024 x 16384) ----
    GM(WvT, Xbf, A1, D2_, N_, D2_, D2_, D2_, N_, 0, 0, 0, 1, 0, 1.f, nullptr, 0, nullptr, 1);

    // ---- ksum (before F2 region is reused); KVT'[b][m][d] = sum_l
    //      phi_kT[m][bL+l] * vT[d][bL+l]  (256 x 1024 per batch) ----
    ksum_k<<<B_ * M_, blk, 0, stream>>>(F2, ksum);
    GM(F2, A1, KVT, M_, D2_, L_, N_, N_, D2_, L_, L_, (long long)M_ * D2_, B_,
       0, 1.f, nullptr, 0, nullptr, 1);

    // ---- Wo folding: G[b][o][m] = sum_d WoT[o][d] * KVT'[b][m][d]
    //      (1024 x 256 per batch, ldc=256, into F2 region -- phi_kT dead) ----
    ushort_t* Gb = F2;
    GM(WoT, KVT, Gb, D2_, M_, D2_, D2_, D2_, M_,
       0, (long long)M_ * D2_, (long long)D2_ * M_, B_,
       0, 1.f, nullptr, 0, nullptr, 1);

    // ---- den; yo_bf[b][n][o] = (sum_m phi_q[n][m]*G[b][o][m])/(den+eps)
    //      K=256 -> gemm_mfma (1024 wgs); bf16 out into P region ----
    den_k<<<N_ / 4, blk, 0, stream>>>(F1, ksum, den);
    GM(F1, Gb, P, L_, D2_, M_, M_, M_, D2_, (long long)L_ * M_,
       (long long)D2_ * M_, (long long)L_ * D2_, B_, 2, 1.f, den, L_, nullptr, 1);

    // ---- attn modrelu over full N (yo read as bf16) ----
    modrelu_attn<<<N_ * D_ / 256, blk, 0, stream>>>(
        zr, zi, (const ushort_t*)P, b_attn, Xbf);

    // ---- combined FFN weights into F1/F2 (phi/G buffers dead) ----
    build_wc1T<<<dim3(32, 128), blk, 0, stream>>>(W1r, W1i, F1);
    build_wc2T<<<dim3(128, 32), blk, 0, stream>>>(W2r, W2i, F2);

    // ---- FFN + final modrelu, N_/RCH chunks ----
    // FFN2 (rows x 1024, K=4096) only fills 128 wgs at 256^2 -> split-K=2:
    // seed Fb with bias, both K-halves atomicAdd (grid 4 x rows/256 x 2).
    for (int c = 0; c < N_ / RCH; ++c) {
        const long long ro = (long long)c * RCH;
        GM(Xbf + ro * D2_, F1, Hb, RCH, 2 * H_, D2_, D2_, D2_, 2 * H_,
           0, 0, 0, 1, 3, 1.f, nullptr, 0, bc1, 1);
        if (RCH == 8192) {
            seed_c<<<RCH * D2_ / 256, blk, 0, stream>>>(bc2, Fb);
            dim3 grid2(D2_ / 256, RCH / 256, 2);
            gemm256<<<grid2, dim3(512), 0, stream>>>(
                Hb, F2, Fb, 2 * H_, 2 * H_, 2 * H_, D2_,
                0, 0, 0, 4, 1.f, nullptr, 0, bc2, 0, 2);
        } else {
            GM(Hb, F2, Fb, RCH, D2_, 2 * H_, 2 * H_, 2 * H_, D2_,
               0, 0, 0, 1, 4, 1.f, nullptr, 0, bc2, 0);
        }
        modrelu_out<<<RCH * D_ / 256, blk, 0, stream>>>(
            Xbf + ro * D2_, Fb, b_ffn, (float*)d_out + ro * D2_);
    }

    (void)in_sizes; (void)n_in; (void)out_size;
}

// Round 12
// 985.245 us; speedup vs baseline: 1.0799x; 1.0799x over previous
//
#include <hip/hip_runtime.h>
#include <math.h>

#define B_ 8
#define L_ 2048
#define D_ 512
#define M_ 256
#define D2_ 1024
#define H_ 2048
#define N_ 16384          // B_*L_
#define EPS_ 1e-6f

typedef __attribute__((ext_vector_type(8))) short bf16x8;
typedef __attribute__((ext_vector_type(4))) float f32x4;
typedef unsigned short ushort_t;
typedef unsigned int uint_t;

// s_waitcnt immediates (gfx9 encoding): lgkmcnt=0xF(no wait), expcnt=7(no wait)
#define WAITCNT_VM4 0x0F74
#define WAITCNT_VM2 0x0F72
#define WAITCNT_VM0 0x0F70

__device__ __forceinline__ ushort_t f2bf(float f) {
    uint_t u = __float_as_uint(f);
    u += 0x7FFFu + ((u >> 16) & 1u);        // round-to-nearest-even
    return (ushort_t)(u >> 16);
}
__device__ __forceinline__ float bf2f(ushort_t u) {
    return __uint_as_float(((uint_t)u) << 16);
}
__device__ __forceinline__ void gload_lds16(const void* g, void* l) {
    __builtin_amdgcn_global_load_lds(
        (const __attribute__((address_space(1))) void*)g,
        (__attribute__((address_space(3))) void*)l, 16, 0, 0);
}

// ---------------------------------------------------------------------------
// bf16 MFMA GEMM, 128x128 tile, BK=32, 2 LDS buffers (32 KiB), 256 thr.
// Used for narrow-grid GEMMs (pq, pkT, KVT', G). K%64==0, rows/cols%128==0.
// ---------------------------------------------------------------------------
__global__ __launch_bounds__(256)
void gemm_mfma(const ushort_t* __restrict__ A, const ushort_t* __restrict__ Bm,
               void* __restrict__ Cp, int K, int lda, int ldb, int ldc,
               long long sA, long long sB, long long sC,
               int epi, float alpha, const float* __restrict__ aux,
               int auxStride, const float* __restrict__ bias, int obf)
{
    __shared__ ushort_t As[2][128 * 32];
    __shared__ ushort_t Bs[2][128 * 32];

    const int bz = blockIdx.z;
    A  += (long long)bz * sA;
    Bm += (long long)bz * sB;
    const int row0 = blockIdx.y * 128;
    const int col0 = blockIdx.x * 128;

    const int tid  = threadIdx.x;
    const int lane = tid & 63;
    const int wave = tid >> 6;
    const int wr = wave >> 1, wc = wave & 1;

    const int srow = tid >> 2;
    const int skol = (((tid & 3) ^ ((tid >> 3) & 3)) * 8);

    f32x4 acc[4][4];
    #pragma unroll
    for (int i = 0; i < 4; ++i)
        #pragma unroll
        for (int j = 0; j < 4; ++j)
            acc[i][j] = (f32x4){0.f, 0.f, 0.f, 0.f};

    const int fr = lane & 15;     // row/col within 16-tile
    const int fq = lane >> 4;     // k-quad
    const int koff = ((fq ^ ((fr >> 1) & 3))) * 8;

    const int nT = K >> 5;        // K-steps of 32; nT even (K%64==0)

    auto issue = [&](int t, ushort_t* Ad, ushort_t* Bd) {
        const int k0 = t << 5;
        gload_lds16(A + (long long)(row0 + srow) * lda + k0 + skol,
                    Ad + (wave * 16) * 32);
        gload_lds16(A + (long long)(row0 + 64 + srow) * lda + k0 + skol,
                    Ad + (64 + wave * 16) * 32);
        gload_lds16(Bm + (long long)(col0 + srow) * ldb + k0 + skol,
                    Bd + (wave * 16) * 32);
        gload_lds16(Bm + (long long)(col0 + 64 + srow) * ldb + k0 + skol,
                    Bd + (64 + wave * 16) * 32);
    };

    auto body = [&](int t, const ushort_t* Ac, const ushort_t* Bc,
                    ushort_t* An, ushort_t* Bn) {
        if (t + 1 < nT) {
            issue(t + 1, An, Bn);                      // buf^1: readers passed
            __builtin_amdgcn_s_waitcnt(WAITCNT_VM4);   //   body(t-1)'s barrier
        } else {
            __builtin_amdgcn_s_waitcnt(WAITCNT_VM0);
        }
        __builtin_amdgcn_s_barrier();

        bf16x8 a[4], b[4];
        #pragma unroll
        for (int i = 0; i < 4; ++i)
            a[i] = *(const bf16x8*)&Ac[(wr * 64 + i * 16 + fr) * 32 + koff];
        #pragma unroll
        for (int j = 0; j < 4; ++j)
            b[j] = *(const bf16x8*)&Bc[(wc * 64 + j * 16 + fr) * 32 + koff];
        #pragma unroll
        for (int i = 0; i < 4; ++i)
            #pragma unroll
            for (int j = 0; j < 4; ++j)
                acc[i][j] = __builtin_amdgcn_mfma_f32_16x16x32_bf16(
                    a[i], b[j], acc[i][j], 0, 0, 0);
        __builtin_amdgcn_s_barrier();
    };

    issue(0, As[0], Bs[0]);
    for (int t = 0; t < nT; t += 2) {
        body(t,     As[0], Bs[0], As[1], Bs[1]);
        body(t + 1, As[1], Bs[1], As[0], Bs[0]);
    }

    // epilogue: C/D layout col=lane&15, row=(lane>>4)*4+reg
    const int gr0 = row0 + wr * 64;
    const int gc0 = col0 + wc * 64;
    #pragma unroll
    for (int i = 0; i < 4; ++i) {
        #pragma unroll
        for (int r = 0; r < 4; ++r) {
            const int row = gr0 + i * 16 + fq * 4 + r;
            float raux = 0.f;
            if (epi == 1 || epi == 2) raux = aux[(long long)bz * auxStride + row];
            #pragma unroll
            for (int j = 0; j < 4; ++j) {
                const int col = gc0 + j * 16 + fr;
                float v = acc[i][j][r];
                if (epi == 0)      v *= alpha;
                else if (epi == 1) v -= 0.5f * raux;
                else if (epi == 2) v = v / (raux + EPS_);
                else if (epi == 5) v -= 0.5f * aux[(long long)bz * auxStride + col];
                else if (epi == 3) { v += bias[col]; v = v > 0.f ? v : 0.f; }
                else if (epi == 4) v += bias[col];
                const long long off = (long long)bz * sC + (long long)row * ldc + col;
                if (obf) ((ushort_t*)Cp)[off] = f2bf(v);
                else     ((float*)Cp)[off] = v;
            }
        }
    }
}

// ---------------------------------------------------------------------------
// 256x256 bf16 GEMM, 16-WAVE version: 1024 thr = 16 waves (4M x 4N), BK=32,
// 2 LDS buffers = 64 KiB, per-wave output 64x64 (acc[4][4], ~100 VGPR).
//
// WHY 16 waves: every prior 256^2 variant ran 8 waves = 2 waves/SIMD at
// 1 block/CU and pinned at MfmaUtil <=23% (rounds 2-11); 2-blocks/CU is
// impossible at 256^2 (round 6: 128-reg accumulator spills). 16 waves give
// 4 waves/SIMD of latency hiding INSIDE the one block -- per-wave footprint
// equals the proven gemm_mfma wave (acc 64 + frags ~32 VGPR < 128 cap).
// LDS-BW check: 128 KB ds_read per BK32-step / 256 B/cyc = 512 cyc vs
// ~1242 cyc MFMA per SIMD -- not binding.
//
// Loop = gemm_mfma's proven 2-barrier body scaled up: stage(t+1) is exactly
// 2 gload_lds (1024 lanes x 16B = one full 256x32 panel each); vmcnt(2)
// lands tile t. WAR argument identical (stage into buf^1 whose readers all
// passed body(t-1)'s trailing barrier). Swizzle involution identical:
// (tid>>3)&3 == (srow>>1)&3 holds at 1024 thr; read rows wr*64+i*16+fr
// give (row>>1)&3 == (fr>>1)&3 for wr in [0,4).
//
// Split-K (ksplit>1): blockIdx.z = batch*ksplit + kz; epilogue atomicAdds
// fp32 into pre-seeded C (seed_c). Requires fp32 out.
// Requires rows%256==0, cols%256==0, (K/ksplit)%64==0.
// ---------------------------------------------------------------------------
__global__ __launch_bounds__(1024)
void gemm256(const ushort_t* __restrict__ A, const ushort_t* __restrict__ Bm,
             void* __restrict__ Cp, int K, int lda, int ldb, int ldc,
             long long sA, long long sB, long long sC,
             int epi, float alpha, const float* __restrict__ aux,
             int auxStride, const float* __restrict__ bias, int obf,
             int ksplit)
{
    __shared__ ushort_t As[2][256 * 32];
    __shared__ ushort_t Bs[2][256 * 32];

    const int bzf = blockIdx.z;
    const int bz = bzf / ksplit;        // batch
    const int kz = bzf - bz * ksplit;   // K-split index
    const int Kh = K / ksplit;

    A  += (long long)bz * sA + (long long)kz * Kh;
    Bm += (long long)bz * sB + (long long)kz * Kh;
    const int row0 = blockIdx.y * 256;
    const int col0 = blockIdx.x * 256;

    const int tid  = threadIdx.x;
    const int lane = tid & 63;
    const int wave = tid >> 6;          // 0..15
    const int wr   = wave >> 2;         // 0..3  (M quarter)
    const int wc   = wave & 3;          // 0..3  (N quarter)

    const int srow = tid >> 2;          // 0..255
    const int skol = (((tid & 3) ^ ((tid >> 3) & 3)) << 3);

    const int fr = lane & 15;
    const int fq = lane >> 4;
    const int koff = ((fq ^ ((fr >> 1) & 3)) << 3);

    const int nT = Kh >> 5;             // K-steps of 32; nT even (Kh%64==0)

    f32x4 acc[4][4];
    #pragma unroll
    for (int i = 0; i < 4; ++i)
        #pragma unroll
        for (int j = 0; j < 4; ++j)
            acc[i][j] = (f32x4){0.f, 0.f, 0.f, 0.f};

    auto issue = [&](int t, ushort_t* Ad, ushort_t* Bd) {
        const int k0 = t << 5;
        gload_lds16(A + (long long)(row0 + srow) * lda + k0 + skol,
                    Ad + (wave * 16) * 32);
        gload_lds16(Bm + (long long)(col0 + srow) * ldb + k0 + skol,
                    Bd + (wave * 16) * 32);
    };

    auto body = [&](int t, const ushort_t* Ac, const ushort_t* Bc,
                    ushort_t* An, ushort_t* Bn) {
        if (t + 1 < nT) {
            issue(t + 1, An, Bn);                      // buf^1: readers passed
            __builtin_amdgcn_s_waitcnt(WAITCNT_VM2);   //   body(t-1)'s barrier
        } else {
            __builtin_amdgcn_s_waitcnt(WAITCNT_VM0);
        }
        __builtin_amdgcn_s_barrier();

        bf16x8 a[4], b[4];
        #pragma unroll
        for (int i = 0; i < 4; ++i)
            a[i] = *(const bf16x8*)&Ac[(wr * 64 + i * 16 + fr) * 32 + koff];
        #pragma unroll
        for (int j = 0; j < 4; ++j)
            b[j] = *(const bf16x8*)&Bc[(wc * 64 + j * 16 + fr) * 32 + koff];
        __builtin_amdgcn_s_setprio(1);
        #pragma unroll
        for (int i = 0; i < 4; ++i)
            #pragma unroll
            for (int j = 0; j < 4; ++j)
                acc[i][j] = __builtin_amdgcn_mfma_f32_16x16x32_bf16(
                    a[i], b[j], acc[i][j], 0, 0, 0);
        __builtin_amdgcn_s_setprio(0);
        __builtin_amdgcn_s_barrier();
    };

    issue(0, As[0], Bs[0]);
    for (int t = 0; t < nT; t += 2) {
        body(t,     As[0], Bs[0], As[1], Bs[1]);
        body(t + 1, As[1], Bs[1], As[0], Bs[0]);
    }

    // epilogue: C/D layout col=lane&15, row=(lane>>4)*4+reg
    const int gr0 = row0 + wr * 64;
    const int gc0 = col0 + wc * 64;
    #pragma unroll
    for (int i = 0; i < 4; ++i) {
        #pragma unroll
        for (int r = 0; r < 4; ++r) {
            const int row = gr0 + i * 16 + fq * 4 + r;
            float raux = 0.f;
            if (epi == 1 || epi == 2) raux = aux[(long long)bz * auxStride + row];
            #pragma unroll
            for (int j = 0; j < 4; ++j) {
                const int col = gc0 + j * 16 + fr;
                float v = acc[i][j][r];
                const long long off = (long long)bz * sC + (long long)row * ldc + col;
                if (ksplit > 1) {
                    // C pre-seeded (bias or zero); fp32 accumulate
                    atomicAdd((float*)Cp + off, v * alpha);
                    continue;
                }
                if (epi == 0)      v *= alpha;
                else if (epi == 1) v -= 0.5f * raux;
                else if (epi == 2) v = v / (raux + EPS_);
                else if (epi == 5) v -= 0.5f * aux[(long long)bz * auxStride + col];
                else if (epi == 3) { v += bias[col]; v = v > 0.f ? v : 0.f; }
                else if (epi == 4) v += bias[col];
                if (obf) ((ushort_t*)Cp)[off] = f2bf(v);
                else     ((float*)Cp)[off] = v;
            }
        }
    }
}

// seed C rows with bias[col] (bias!=null) or zero, ldc = 1024
__global__ __launch_bounds__(256)
void seed_c(const float* __restrict__ bias, float* __restrict__ C)
{
    const long long t = (long long)blockIdx.x * 256 + threadIdx.x;
    C[t] = bias ? bias[(int)(t & (D2_ - 1))] : 0.f;
}

// ---------- build / convert kernels ----------------------------------------

// 1024x1024 fp32 W -> bf16 W^T  (out[n][k] = W[k][n])
__global__ __launch_bounds__(256)
void transpose_cvt_sq(const float* __restrict__ W, ushort_t* __restrict__ out)
{
    __shared__ float S[32][33];
    const int tx = threadIdx.x & 31, ty = threadIdx.x >> 5;
    const int n0 = blockIdx.x * 32, k0 = blockIdx.y * 32;
    #pragma unroll
    for (int r = 0; r < 4; ++r)
        S[ty + 8 * r][tx] = W[(long long)(k0 + ty + 8 * r) * 1024 + n0 + tx];
    __syncthreads();
    #pragma unroll
    for (int r = 0; r < 4; ++r)
        out[(long long)(n0 + ty + 8 * r) * 1024 + k0 + tx] = f2bf(S[tx][ty + 8 * r]);
}

// wc1T (4096 x 1024): out[j][i] of combined [[W1r,W1i],[-W1i,W1r]]
__global__ __launch_bounds__(256)
void build_wc1T(const float* __restrict__ W1r, const float* __restrict__ W1i,
                ushort_t* __restrict__ out)
{
    __shared__ float S[32][33];
    const int tx = threadIdx.x & 31, ty = threadIdx.x >> 5;
    const int i0 = blockIdx.x * 32, j0 = blockIdx.y * 32;
    #pragma unroll
    for (int r = 0; r < 4; ++r) {
        const int i = i0 + ty + 8 * r, j = j0 + tx;
        float v;
        if (j < H_) v = (i < D_) ? W1r[(long long)i * H_ + j]
                                 : -W1i[(long long)(i - D_) * H_ + j];
        else {
            const int jj = j - H_;
            v = (i < D_) ? W1i[(long long)i * H_ + jj]
                         : W1r[(long long)(i - D_) * H_ + jj];
        }
        S[tx][ty + 8 * r] = v;
    }
    __syncthreads();
    #pragma unroll
    for (int r = 0; r < 4; ++r)
        out[(long long)(j0 + ty + 8 * r) * 1024 + i0 + tx] = f2bf(S[ty + 8 * r][tx]);
}

// wc2T (1024 x 4096): out[j][i] of combined [[W2r,W2i],[-W2i,W2r]]
__global__ __launch_bounds__(256)
void build_wc2T(const float* __restrict__ W2r, const float* __restrict__ W2i,
                ushort_t* __restrict__ out)
{
    __shared__ float S[32][33];
    const int tx = threadIdx.x & 31, ty = threadIdx.x >> 5;
    const int i0 = blockIdx.x * 32, j0 = blockIdx.y * 32;
    #pragma unroll
    for (int r = 0; r < 4; ++r) {
        const int i = i0 + ty + 8 * r, j = j0 + tx;
        float v;
        if (i < H_) v = (j < D_) ? W2r[(long long)i * D_ + j]
                                 : W2i[(long long)i * D_ + (j - D_)];
        else {
            const int ii = i - H_;
            v = (j < D_) ? -W2i[(long long)ii * D_ + j]
                         : W2r[(long long)ii * D_ + (j - D_)];
        }
        S[tx][ty + 8 * r] = v;
    }
    __syncthreads();
    #pragma unroll
    for (int r = 0; r < 4; ++r)
        out[(long long)(j0 + ty + 8 * r) * 4096 + i0 + tx] = f2bf(S[ty + 8 * r][tx]);
}

__global__ __launch_bounds__(256)
void build_bias(const float* __restrict__ b1r, const float* __restrict__ b1i,
                const float* __restrict__ b2r, const float* __restrict__ b2i,
                float* __restrict__ bc1, float* __restrict__ bc2)
{
    const int t = blockIdx.x * 256 + threadIdx.x;   // grid 16 -> t < 4096
    bc1[t] = (t < H_) ? b1r[t] : b1i[t - H_];
    if (t < D2_) bc2[t] = (t < D_) ? b2r[t] : b2i[t - D_];
}

__global__ __launch_bounds__(256)
void cvt_Wf(const float* __restrict__ Wf, ushort_t* __restrict__ out)
{
    const int t = blockIdx.x * 256 + threadIdx.x;   // 262144
    out[t] = f2bf(Wf[t]);
}

// x_bf (N x D2) = bf16(concat(zr, zi))
__global__ __launch_bounds__(256)
void cvt_x(const float* __restrict__ zr, const float* __restrict__ zi,
           ushort_t* __restrict__ x)
{
    long long t = (long long)blockIdx.x * 256 + threadIdx.x;  // N*D2/4
    long long n = t >> 8;
    int j4 = (int)(t & 255) << 2;
    float4 v;
    if (j4 < D_) v = *(const float4*)(zr + n * D_ + j4);
    else         v = *(const float4*)(zi + n * D_ + (j4 - D_));
    uint2 o;
    o.x = (uint_t)f2bf(v.x) | ((uint_t)f2bf(v.y) << 16);
    o.y = (uint_t)f2bf(v.z) | ((uint_t)f2bf(v.w) << 16);
    *(uint2*)(x + n * D2_ + j4) = o;
}

// ssq[n] = sum_k bf2f(A[n,k])^2, row len 1024, one wave per row
// (k-side only: phi_k uses a GLOBAL max so the row-shift matters; the q-side
//  row-shift cancels under per-row max-subtraction and is not computed.)
__global__ __launch_bounds__(256)
void rowsumsq_bf(const ushort_t* __restrict__ A, float* __restrict__ out)
{
    const int wid = threadIdx.x >> 6, lane = threadIdx.x & 63;
    const long long row = (long long)blockIdx.x * 4 + wid;
    const ushort_t* a = A + row * D2_;
    float s = 0.f;
    #pragma unroll
    for (int h = 0; h < 2; ++h) {
        uint4 u = *(const uint4*)(a + h * 512 + lane * 8);
        const uint_t w[4] = {u.x, u.y, u.z, u.w};
        #pragma unroll
        for (int p = 0; p < 4; ++p) {
            float lo = bf2f((ushort_t)(w[p] & 0xffff));
            float hi = bf2f((ushort_t)(w[p] >> 16));
            s += lo * lo + hi * hi;
        }
    }
    #pragma unroll
    for (int off = 32; off; off >>= 1) s += __shfl_down(s, off, 64);
    if (lane == 0) out[row] = s;
}

// phi_q: per-row max-subtract + exp over M=256, pq fp32 -> bf16 out
__global__ __launch_bounds__(256)
void phi_rowmax_exp(const float* __restrict__ P, ushort_t* __restrict__ out)
{
    const long long row = blockIdx.x;
    const int t = threadIdx.x;
    const float v = P[row * M_ + t];
    float m = v;
    #pragma unroll
    for (int off = 32; off; off >>= 1) m = fmaxf(m, __shfl_down(m, off, 64));
    __shared__ float sm[4];
    const int wid = t >> 6, lane = t & 63;
    if (lane == 0) sm[wid] = m;
    __syncthreads();
    const float mm = fmaxf(fmaxf(sm[0], sm[1]), fmaxf(sm[2], sm[3]));
    out[row * M_ + t] = f2bf(expf(v - mm) * 0.0625f);
}

__global__ __launch_bounds__(256)
void gmax1(const float* __restrict__ P, float* __restrict__ part, int n)
{
    float m = -3.4e38f;
    for (long long i = (long long)blockIdx.x * 256 + threadIdx.x; i < n;
         i += (long long)gridDim.x * 256)
        m = fmaxf(m, P[i]);
    #pragma unroll
    for (int off = 32; off; off >>= 1) m = fmaxf(m, __shfl_down(m, off, 64));
    __shared__ float sm[4];
    const int wid = threadIdx.x >> 6, lane = threadIdx.x & 63;
    if (lane == 0) sm[wid] = m;
    __syncthreads();
    if (threadIdx.x == 0)
        part[blockIdx.x] = fmaxf(fmaxf(sm[0], sm[1]), fmaxf(sm[2], sm[3]));
}

__global__ __launch_bounds__(256)
void gmax2(float* __restrict__ red)
{
    float m = -3.4e38f;
    for (int i = threadIdx.x; i < 1024; i += 256) m = fmaxf(m, red[256 + i]);
    #pragma unroll
    for (int off = 32; off; off >>= 1) m = fmaxf(m, __shfl_down(m, off, 64));
    __shared__ float sm[4];
    const int wid = threadIdx.x >> 6, lane = threadIdx.x & 63;
    if (lane == 0) sm[wid] = m;
    __syncthreads();
    if (threadIdx.x == 0) red[0] = fmaxf(fmaxf(sm[0], sm[1]), fmaxf(sm[2], sm[3]));
}

// phi_kT = bf16(exp(pkT - gmax)/16)
__global__ __launch_bounds__(256)
void phikT_exp(const float* __restrict__ P, const float* __restrict__ red,
               ushort_t* __restrict__ out)
{
    const long long i = (long long)blockIdx.x * 256 + threadIdx.x;
    out[i] = f2bf(expf(P[i] - red[0]) * 0.0625f);
}

// ksum[b,m] = sum_l phi_kT[m, b*L+l]; one block per (b,m)
__global__ __launch_bounds__(256)
void ksum_k(const ushort_t* __restrict__ phikT, float* __restrict__ ks)
{
    const int b = blockIdx.x >> 8, m = blockIdx.x & 255;
    const ushort_t* p = phikT + (long long)m * N_ + b * L_;
    uint4 u = *(const uint4*)(p + threadIdx.x * 8);
    const uint_t w[4] = {u.x, u.y, u.z, u.w};
    float s = 0.f;
    #pragma unroll
    for (int q = 0; q < 4; ++q)
        s += bf2f((ushort_t)(w[q] & 0xffff)) + bf2f((ushort_t)(w[q] >> 16));
    #pragma unroll
    for (int off = 32; off; off >>= 1) s += __shfl_down(s, off, 64);
    __shared__ float sm[4];
    const int wid = threadIdx.x >> 6, lane = threadIdx.x & 63;
    if (lane == 0) sm[wid] = s;
    __syncthreads();
    if (threadIdx.x == 0)
        ks[blockIdx.x] = sm[0] + sm[1] + sm[2] + sm[3];
}

// den[n] = sum_m phi_q_bf[n,m]*ksum[b,m]; one wave per row
__global__ __launch_bounds__(256)
void den_k(const ushort_t* __restrict__ phiq, const float* __restrict__ ks,
           float* __restrict__ den)
{
    const int wid = threadIdx.x >> 6, lane = threadIdx.x & 63;
    const long long n = (long long)blockIdx.x * 4 + wid;
    const int b = (int)(n >> 11);
    uint2 u = *(const uint2*)(phiq + n * M_ + lane * 4);
    float4 kk = *(const float4*)(ks + b * M_ + lane * 4);
    float s = bf2f((ushort_t)(u.x & 0xffff)) * kk.x
            + bf2f((ushort_t)(u.x >> 16)) * kk.y
            + bf2f((ushort_t)(u.y & 0xffff)) * kk.z
            + bf2f((ushort_t)(u.y >> 16)) * kk.w;
    #pragma unroll
    for (int off = 32; off; off >>= 1) s += __shfl_down(s, off, 64);
    if (lane == 0) den[n] = s;
}

// zst_bf = bf16(modrelu(z + yo)); yo is bf16 (N x D2), full-N launch
__global__ __launch_bounds__(256)
void modrelu_attn(const float* __restrict__ zr, const float* __restrict__ zi,
                  const ushort_t* __restrict__ yo, const float* __restrict__ b_attn,
                  ushort_t* __restrict__ zst)
{
    const long long t = (long long)blockIdx.x * 256 + threadIdx.x;
    const long long n = t >> 9; const int d = (int)(t & 511);
    const float ar = zr[t] + bf2f(yo[n * D2_ + d]);
    const float ai = zi[t] + bf2f(yo[n * D2_ + D_ + d]);
    const float mag = sqrtf(ar * ar + ai * ai + EPS_);
    const float s = fmaxf(mag + b_attn[d], 0.f) / mag;
    zst[n * D2_ + d]      = f2bf(ar * s);
    zst[n * D2_ + D_ + d] = f2bf(ai * s);
}

// out chunk = modrelu(zst + f) interleaved; zst(bf16)/f/out pre-offset
__global__ __launch_bounds__(256)
void modrelu_out(const ushort_t* __restrict__ zst, const float* __restrict__ f,
                 const float* __restrict__ b_ffn, float* __restrict__ out)
{
    const long long t = (long long)blockIdx.x * 256 + threadIdx.x;
    const long long n = t >> 9; const int d = (int)(t & 511);
    const float ar = bf2f(zst[n * D2_ + d])      + f[n * D2_ + d];
    const float ai = bf2f(zst[n * D2_ + D_ + d]) + f[n * D2_ + D_ + d];
    const float mag = sqrtf(ar * ar + ai * ai + EPS_);
    const float s = fmaxf(mag + b_ffn[d], 0.f) / mag;
    out[t * 2]     = ar * s;
    out[t * 2 + 1] = ai * s;
}

extern "C" void kernel_launch(void* const* d_in, const int* in_sizes, int n_in,
                              void* d_out, int out_size, void* d_ws, size_t ws_size,
                              hipStream_t stream)
{
    const float* zr    = (const float*)d_in[0];
    const float* zi    = (const float*)d_in[1];
    const float* Wq    = (const float*)d_in[2];
    const float* Wk    = (const float*)d_in[3];
    const float* Wv    = (const float*)d_in[4];
    const float* Wo    = (const float*)d_in[5];
    const float* Wf    = (const float*)d_in[6];
    const float* b_attn= (const float*)d_in[7];
    const float* W1r   = (const float*)d_in[8];
    const float* W1i   = (const float*)d_in[9];
    const float* b1r   = (const float*)d_in[10];
    const float* b1i   = (const float*)d_in[11];
    const float* W2r   = (const float*)d_in[12];
    const float* W2i   = (const float*)d_in[13];
    const float* b2r   = (const float*)d_in[14];
    const float* b2i   = (const float*)d_in[15];
    const float* b_ffn = (const float*)d_in[16];

    char* w = (char*)d_ws;
    // Attention-phase layout (~124 MB):
    ushort_t* Xbf = (ushort_t*)(w + 0LL);          // x_bf -> zst_bf (33.55 MB)
    ushort_t* A1  = (ushort_t*)(w + 33554432LL);   // q/k -> vT (33.55 MB)
    float*    P   = (float*)   (w + 67108864LL);   // pq/pkT -> yo_bf16 (16.8)
    ushort_t* WqT = (ushort_t*)(w + 83886080LL);   // after P (dead then)
    ushort_t* WkT = (ushort_t*)(w + 85983232LL);
    ushort_t* WvT = (ushort_t*)(w + 88080384LL);
    ushort_t* Wfb = (ushort_t*)(w + 90177536LL);
    ushort_t* F1  = (ushort_t*)(w + 100663296LL);  // phi_q_bf -> wc1T (8.39 MB)
    ushort_t* F2  = (ushort_t*)(w + 109051904LL);  // phi_kT -> G -> wc2T (8.39)
    ushort_t* WoT = (ushort_t*)(w + 117440512LL);  // 2 MB
    ushort_t* KVT = (ushort_t*)(w + 119537664LL);  // KVT' (8,256,1024) bf16, 4MB
    float* ssqk = (float*)(w + 123797504LL);
    float* den  = (float*)(w + 123863040LL);
    float* ksum = (float*)(w + 123928576LL);
    float* red  = (float*)(w + 123936768LL);

    // FFN-phase layout, gated on ws_size:
    const bool big = ws_size >= 152000000ULL;
    const int  RCH = big ? 8192 : 4096;
    ushort_t* Hb = (ushort_t*)(w + 33554432LL);
    float* Fb  = big ? (float*)(w + 117440512LL) : (float*)(w + 67108864LL);
    float* bc1 = big ? (float*)(w + 150994944LL) : (float*)(w + 123944960LL);
    float* bc2 = big ? (float*)(w + 151011328LL) : (float*)(w + 123961344LL);

    const float scl = 0.1767766952966369f;  // D2^-0.25
    dim3 blk(256);

    // Route: 256x256 16-wave kernel when the grid is wide enough (>=128 wgs)
    // and dims allow; else the 128x128 2-buffer kernel.
    auto GM = [&](const ushort_t* A, const ushort_t* Bm, void* C,
                  int rows, int cols, int K, int lda, int ldb, int ldc,
                  long long sA, long long sB, long long sC, int nb,
                  int epi, float alpha, const float* aux, int auxStride,
                  const float* bias, int obf) {
        const long long wg256 = (long long)(cols >> 8) * (rows >> 8) * nb;
        if ((rows & 255) == 0 && (cols & 255) == 0 && (K & 127) == 0 &&
            wg256 >= 128) {
            dim3 grid(cols / 256, rows / 256, nb);
            gemm256<<<grid, dim3(1024), 0, stream>>>(A, Bm, C, K, lda, ldb, ldc,
                                                     sA, sB, sC, epi, alpha, aux,
                                                     auxStride, bias, obf, 1);
        } else {
            dim3 grid(cols / 128, rows / 128, nb);
            gemm_mfma<<<grid, blk, 0, stream>>>(A, Bm, C, K, lda, ldb, ldc,
                                                sA, sB, sC, epi, alpha, aux,
                                                auxStride, bias, obf);
        }
    };

    // ---- one-time weight prep + input convert ----
    transpose_cvt_sq<<<dim3(32, 32), blk, 0, stream>>>(Wq, WqT);
    transpose_cvt_sq<<<dim3(32, 32), blk, 0, stream>>>(Wk, WkT);
    transpose_cvt_sq<<<dim3(32, 32), blk, 0, stream>>>(Wv, WvT);
    transpose_cvt_sq<<<dim3(32, 32), blk, 0, stream>>>(Wo, WoT);
    cvt_Wf<<<1024, blk, 0, stream>>>(Wf, Wfb);
    build_bias<<<16, blk, 0, stream>>>(b1r, b1i, b2r, b2i, bc1, bc2);
    cvt_x<<<N_ * (D2_ / 4) / 256, blk, 0, stream>>>(zr, zi, Xbf);

    // ---- q phase: q_bf = x@WqT*scl; pq = q@Wf^T (the -0.5*ssqq row-shift
    //      cancels under per-row max-subtraction -- not computed); phi_q ----
    GM(Xbf, WqT, A1, N_, D2_, D2_, D2_, D2_, D2_, 0, 0, 0, 1, 0, scl, nullptr, 0, nullptr, 1);
    GM(A1, Wfb, P, N_, M_, D2_, D2_, D2_, M_, 0, 0, 0, 1, 0, 1.f, nullptr, 0, nullptr, 0);
    phi_rowmax_exp<<<N_, blk, 0, stream>>>(P, F1);

    // ---- k phase: k_bf; ssqk; pkT = Wf@k^T - 0.5ssqk[col]; phi_kT ----
    GM(Xbf, WkT, A1, N_, D2_, D2_, D2_, D2_, D2_, 0, 0, 0, 1, 0, scl, nullptr, 0, nullptr, 1);
    rowsumsq_bf<<<N_ / 4, blk, 0, stream>>>(A1, ssqk);
    GM(Wfb, A1, P, M_, N_, D2_, D2_, D2_, N_, 0, 0, 0, 1, 5, 1.f, ssqk, 0, nullptr, 0);
    gmax1<<<1024, blk, 0, stream>>>(P, red + 256, M_ * N_);
    gmax2<<<1, blk, 0, stream>>>(red);
    phikT_exp<<<M_ * N_ / 256, blk, 0, stream>>>(P, red, F2);

    // ---- vT = Wv^T @ x^T (1024 x 16384) ----
    GM(WvT, Xbf, A1, D2_, N_, D2_, D2_, D2_, N_, 0, 0, 0, 1, 0, 1.f, nullptr, 0, nullptr, 1);

    // ---- ksum (before F2 region is reused); KVT'[b][m][d] = sum_l
    //      phi_kT[m][bL+l] * vT[d][bL+l]  (256 x 1024 per batch) ----
    ksum_k<<<B_ * M_, blk, 0, stream>>>(F2, ksum);
    GM(F2, A1, KVT, M_, D2_, L_, N_, N_, D2_, L_, L_, (long long)M_ * D2_, B_,
       0, 1.f, nullptr, 0, nullptr, 1);

    // ---- Wo folding: G[b][o][m] = sum_d WoT[o][d] * KVT'[b][m][d]
    //      (1024 x 256 per batch, ldc=256, into F2 region -- phi_kT dead) ----
    ushort_t* Gb = F2;
    GM(WoT, KVT, Gb, D2_, M_, D2_, D2_, D2_, M_,
       0, (long long)M_ * D2_, (long long)D2_ * M_, B_,
       0, 1.f, nullptr, 0, nullptr, 1);

    // ---- den; yo_bf[b][n][o] = (sum_m phi_q[n][m]*G[b][o][m])/(den+eps)
    //      bf16 out into P region ----
    den_k<<<N_ / 4, blk, 0, stream>>>(F1, ksum, den);
    GM(F1, Gb, P, L_, D2_, M_, M_, M_, D2_, (long long)L_ * M_,
       (long long)D2_ * M_, (long long)L_ * D2_, B_, 2, 1.f, den, L_, nullptr, 1);

    // ---- attn modrelu over full N (yo read as bf16) ----
    modrelu_attn<<<N_ * D_ / 256, blk, 0, stream>>>(
        zr, zi, (const ushort_t*)P, b_attn, Xbf);

    // ---- combined FFN weights into F1/F2 (phi/G buffers dead) ----
    build_wc1T<<<dim3(32, 128), blk, 0, stream>>>(W1r, W1i, F1);
    build_wc2T<<<dim3(128, 32), blk, 0, stream>>>(W2r, W2i, F2);

    // ---- FFN + final modrelu, N_/RCH chunks ----
    // FFN2 (rows x 1024, K=4096) only fills 128 wgs at 256^2 -> split-K=2:
    // seed Fb with bias, both K-halves atomicAdd (grid 4 x rows/256 x 2).
    for (int c = 0; c < N_ / RCH; ++c) {
        const long long ro = (long long)c * RCH;
        GM(Xbf + ro * D2_, F1, Hb, RCH, 2 * H_, D2_, D2_, D2_, 2 * H_,
           0, 0, 0, 1, 3, 1.f, nullptr, 0, bc1, 1);
        if (RCH == 8192) {
            seed_c<<<RCH * D2_ / 256, blk, 0, stream>>>(bc2, Fb);
            dim3 grid2(D2_ / 256, RCH / 256, 2);
            gemm256<<<grid2, dim3(1024), 0, stream>>>(
                Hb, F2, Fb, 2 * H_, 2 * H_, 2 * H_, D2_,
                0, 0, 0, 4, 1.f, nullptr, 0, bc2, 0, 2);
        } else {
            GM(Hb, F2, Fb, RCH, D2_, 2 * H_, 2 * H_, 2 * H_, D2_,
               0, 0, 0, 1, 4, 1.f, nullptr, 0, bc2, 0);
        }
        modrelu_out<<<RCH * D_ / 256, blk, 0, stream>>>(
            Xbf + ro * D2_, Fb, b_ffn, (float*)d_out + ro * D2_);
    }

    (void)in_sizes; (void)n_in; (void)out_size;
}

// Round 13
// 979.144 us; speedup vs baseline: 1.0866x; 1.0062x over previous
//
#include <hip/hip_runtime.h>
#include <math.h>

#define B_ 8
#define L_ 2048
#define D_ 512
#define M_ 256
#define D2_ 1024
#define H_ 2048
#define N_ 16384          // B_*L_
#define EPS_ 1e-6f

typedef __attribute__((ext_vector_type(8))) short bf16x8;
typedef __attribute__((ext_vector_type(4))) float f32x4;
typedef unsigned short ushort_t;
typedef unsigned int uint_t;

// s_waitcnt immediates (gfx9 encoding): lgkmcnt=0xF(no wait), expcnt=7(no wait)
#define WAITCNT_VM4 0x0F74
#define WAITCNT_VM2 0x0F72
#define WAITCNT_VM0 0x0F70

__device__ __forceinline__ ushort_t f2bf(float f) {
    uint_t u = __float_as_uint(f);
    u += 0x7FFFu + ((u >> 16) & 1u);        // round-to-nearest-even
    return (ushort_t)(u >> 16);
}
__device__ __forceinline__ float bf2f(ushort_t u) {
    return __uint_as_float(((uint_t)u) << 16);
}
__device__ __forceinline__ void gload_lds16(const void* g, void* l) {
    __builtin_amdgcn_global_load_lds(
        (const __attribute__((address_space(1))) void*)g,
        (__attribute__((address_space(3))) void*)l, 16, 0, 0);
}

// ---------------------------------------------------------------------------
// bf16 MFMA GEMM, 128x128 tile, BK=32, 2 LDS buffers (32 KiB), 256 thr.
// Used for narrow-grid GEMMs (pq, pkT, KVT', G). K%64==0, rows/cols%128==0.
// ---------------------------------------------------------------------------
__global__ __launch_bounds__(256)
void gemm_mfma(const ushort_t* __restrict__ A, const ushort_t* __restrict__ Bm,
               void* __restrict__ Cp, int K, int lda, int ldb, int ldc,
               long long sA, long long sB, long long sC,
               int epi, float alpha, const float* __restrict__ aux,
               int auxStride, const float* __restrict__ bias, int obf)
{
    __shared__ ushort_t As[2][128 * 32];
    __shared__ ushort_t Bs[2][128 * 32];

    const int bz = blockIdx.z;
    A  += (long long)bz * sA;
    Bm += (long long)bz * sB;
    const int row0 = blockIdx.y * 128;
    const int col0 = blockIdx.x * 128;

    const int tid  = threadIdx.x;
    const int lane = tid & 63;
    const int wave = tid >> 6;
    const int wr = wave >> 1, wc = wave & 1;

    const int srow = tid >> 2;
    const int skol = (((tid & 3) ^ ((tid >> 3) & 3)) * 8);

    f32x4 acc[4][4];
    #pragma unroll
    for (int i = 0; i < 4; ++i)
        #pragma unroll
        for (int j = 0; j < 4; ++j)
            acc[i][j] = (f32x4){0.f, 0.f, 0.f, 0.f};

    const int fr = lane & 15;     // row/col within 16-tile
    const int fq = lane >> 4;     // k-quad
    const int koff = ((fq ^ ((fr >> 1) & 3))) * 8;

    const int nT = K >> 5;        // K-steps of 32; nT even (K%64==0)

    auto issue = [&](int t, ushort_t* Ad, ushort_t* Bd) {
        const int k0 = t << 5;
        gload_lds16(A + (long long)(row0 + srow) * lda + k0 + skol,
                    Ad + (wave * 16) * 32);
        gload_lds16(A + (long long)(row0 + 64 + srow) * lda + k0 + skol,
                    Ad + (64 + wave * 16) * 32);
        gload_lds16(Bm + (long long)(col0 + srow) * ldb + k0 + skol,
                    Bd + (wave * 16) * 32);
        gload_lds16(Bm + (long long)(col0 + 64 + srow) * ldb + k0 + skol,
                    Bd + (64 + wave * 16) * 32);
    };

    auto body = [&](int t, const ushort_t* Ac, const ushort_t* Bc,
                    ushort_t* An, ushort_t* Bn) {
        if (t + 1 < nT) {
            issue(t + 1, An, Bn);                      // buf^1: readers passed
            __builtin_amdgcn_s_waitcnt(WAITCNT_VM4);   //   body(t-1)'s barrier
        } else {
            __builtin_amdgcn_s_waitcnt(WAITCNT_VM0);
        }
        __builtin_amdgcn_s_barrier();

        bf16x8 a[4], b[4];
        #pragma unroll
        for (int i = 0; i < 4; ++i)
            a[i] = *(const bf16x8*)&Ac[(wr * 64 + i * 16 + fr) * 32 + koff];
        #pragma unroll
        for (int j = 0; j < 4; ++j)
            b[j] = *(const bf16x8*)&Bc[(wc * 64 + j * 16 + fr) * 32 + koff];
        #pragma unroll
        for (int i = 0; i < 4; ++i)
            #pragma unroll
            for (int j = 0; j < 4; ++j)
                acc[i][j] = __builtin_amdgcn_mfma_f32_16x16x32_bf16(
                    a[i], b[j], acc[i][j], 0, 0, 0);
        __builtin_amdgcn_s_barrier();
    };

    issue(0, As[0], Bs[0]);
    for (int t = 0; t < nT; t += 2) {
        body(t,     As[0], Bs[0], As[1], Bs[1]);
        body(t + 1, As[1], Bs[1], As[0], Bs[0]);
    }

    // epilogue: C/D layout col=lane&15, row=(lane>>4)*4+reg
    const int gr0 = row0 + wr * 64;
    const int gc0 = col0 + wc * 64;
    #pragma unroll
    for (int i = 0; i < 4; ++i) {
        #pragma unroll
        for (int r = 0; r < 4; ++r) {
            const int row = gr0 + i * 16 + fq * 4 + r;
            float raux = 0.f;
            if (epi == 1 || epi == 2) raux = aux[(long long)bz * auxStride + row];
            #pragma unroll
            for (int j = 0; j < 4; ++j) {
                const int col = gc0 + j * 16 + fr;
                float v = acc[i][j][r];
                if (epi == 0)      v *= alpha;
                else if (epi == 1) v -= 0.5f * raux;
                else if (epi == 2) v = v / (raux + EPS_);
                else if (epi == 5) v -= 0.5f * aux[(long long)bz * auxStride + col];
                else if (epi == 3) { v += bias[col]; v = v > 0.f ? v : 0.f; }
                else if (epi == 4) v += bias[col];
                const long long off = (long long)bz * sC + (long long)row * ldc + col;
                if (obf) ((ushort_t*)Cp)[off] = f2bf(v);
                else     ((float*)Cp)[off] = v;
            }
        }
    }
}

// ---------------------------------------------------------------------------
// 256x256 bf16 GEMM, 16-WAVE version: 1024 thr = 16 waves (4M x 4N), BK=32,
// 2 LDS buffers = 64 KiB, per-wave output 64x64 (acc[4][4], ~60 VGPR).
// Proven round 12: total 1059 -> 985 us, occupancy 21 -> 41%.
//
// T1 (this round): bijective XCD swizzle (m204) of the flat wg id. FFN1's
// FETCH was 153 MB vs ~25 ideal -- consecutive x-ids share an A row-panel
// but default dispatch round-robins them across the 8 non-coherent L2s.
// Chunking consecutive ids onto one XCD fetches each panel once per chunk.
// (Round-3's negative T1 read was taken at FETCH 74 MB / L3-absorbed --
// different regime; split-K grids are order-independent under atomicAdd.)
//
// Loop = gemm_mfma's proven 2-barrier body scaled up: stage(t+1) is exactly
// 2 gload_lds (1024 lanes x 16B = one full 256x32 panel each); vmcnt(2)
// lands tile t. WAR: stage into buf^1 whose readers passed body(t-1)'s
// trailing barrier. Swizzle involution identical to gemm_mfma.
//
// Split-K (ksplit>1): blockIdx.z = batch*ksplit + kz; epilogue atomicAdds
// fp32 into pre-seeded C (seed_c). Requires fp32 out.
// Requires rows%256==0, cols%256==0, (K/ksplit)%64==0.
// ---------------------------------------------------------------------------
__global__ __launch_bounds__(1024)
void gemm256(const ushort_t* __restrict__ A, const ushort_t* __restrict__ Bm,
             void* __restrict__ Cp, int K, int lda, int ldb, int ldc,
             long long sA, long long sB, long long sC,
             int epi, float alpha, const float* __restrict__ aux,
             int auxStride, const float* __restrict__ bias, int obf,
             int ksplit)
{
    __shared__ ushort_t As[2][256 * 32];
    __shared__ ushort_t Bs[2][256 * 32];

    // ---- T1: bijective XCD swizzle of the flat workgroup id (m204) ----
    const int gx = gridDim.x, gy = gridDim.y;
    int fid = blockIdx.x + gx * (blockIdx.y + gy * blockIdx.z);
    const int nwg = gx * gy * gridDim.z;
    const int qch = nwg >> 3, rch = nwg & 7;
    const int xcd = fid & 7, idx = fid >> 3;
    int nid = (xcd < rch ? xcd * (qch + 1) : rch * (qch + 1) + (xcd - rch) * qch)
              + idx;
    const int bx = nid % gx; nid /= gx;
    const int by = nid % gy;
    const int bzf = nid / gy;

    const int bz = bzf / ksplit;        // batch
    const int kz = bzf - bz * ksplit;   // K-split index
    const int Kh = K / ksplit;

    A  += (long long)bz * sA + (long long)kz * Kh;
    Bm += (long long)bz * sB + (long long)kz * Kh;
    const int row0 = by * 256;
    const int col0 = bx * 256;

    const int tid  = threadIdx.x;
    const int lane = tid & 63;
    const int wave = tid >> 6;          // 0..15
    const int wr   = wave >> 2;         // 0..3  (M quarter)
    const int wc   = wave & 3;          // 0..3  (N quarter)

    const int srow = tid >> 2;          // 0..255
    const int skol = (((tid & 3) ^ ((tid >> 3) & 3)) << 3);

    const int fr = lane & 15;
    const int fq = lane >> 4;
    const int koff = ((fq ^ ((fr >> 1) & 3)) << 3);

    const int nT = Kh >> 5;             // K-steps of 32; nT even (Kh%64==0)

    f32x4 acc[4][4];
    #pragma unroll
    for (int i = 0; i < 4; ++i)
        #pragma unroll
        for (int j = 0; j < 4; ++j)
            acc[i][j] = (f32x4){0.f, 0.f, 0.f, 0.f};

    auto issue = [&](int t, ushort_t* Ad, ushort_t* Bd) {
        const int k0 = t << 5;
        gload_lds16(A + (long long)(row0 + srow) * lda + k0 + skol,
                    Ad + (wave * 16) * 32);
        gload_lds16(Bm + (long long)(col0 + srow) * ldb + k0 + skol,
                    Bd + (wave * 16) * 32);
    };

    auto body = [&](int t, const ushort_t* Ac, const ushort_t* Bc,
                    ushort_t* An, ushort_t* Bn) {
        if (t + 1 < nT) {
            issue(t + 1, An, Bn);                      // buf^1: readers passed
            __builtin_amdgcn_s_waitcnt(WAITCNT_VM2);   //   body(t-1)'s barrier
        } else {
            __builtin_amdgcn_s_waitcnt(WAITCNT_VM0);
        }
        __builtin_amdgcn_s_barrier();

        bf16x8 a[4], b[4];
        #pragma unroll
        for (int i = 0; i < 4; ++i)
            a[i] = *(const bf16x8*)&Ac[(wr * 64 + i * 16 + fr) * 32 + koff];
        #pragma unroll
        for (int j = 0; j < 4; ++j)
            b[j] = *(const bf16x8*)&Bc[(wc * 64 + j * 16 + fr) * 32 + koff];
        __builtin_amdgcn_s_setprio(1);
        #pragma unroll
        for (int i = 0; i < 4; ++i)
            #pragma unroll
            for (int j = 0; j < 4; ++j)
                acc[i][j] = __builtin_amdgcn_mfma_f32_16x16x32_bf16(
                    a[i], b[j], acc[i][j], 0, 0, 0);
        __builtin_amdgcn_s_setprio(0);
        __builtin_amdgcn_s_barrier();
    };

    issue(0, As[0], Bs[0]);
    for (int t = 0; t < nT; t += 2) {
        body(t,     As[0], Bs[0], As[1], Bs[1]);
        body(t + 1, As[1], Bs[1], As[0], Bs[0]);
    }

    // epilogue: C/D layout col=lane&15, row=(lane>>4)*4+reg
    const int gr0 = row0 + wr * 64;
    const int gc0 = col0 + wc * 64;
    #pragma unroll
    for (int i = 0; i < 4; ++i) {
        #pragma unroll
        for (int r = 0; r < 4; ++r) {
            const int row = gr0 + i * 16 + fq * 4 + r;
            float raux = 0.f;
            if (epi == 1 || epi == 2) raux = aux[(long long)bz * auxStride + row];
            #pragma unroll
            for (int j = 0; j < 4; ++j) {
                const int col = gc0 + j * 16 + fr;
                float v = acc[i][j][r];
                const long long off = (long long)bz * sC + (long long)row * ldc + col;
                if (ksplit > 1) {
                    // C pre-seeded (bias or zero); fp32 accumulate
                    atomicAdd((float*)Cp + off, v * alpha);
                    continue;
                }
                if (epi == 0)      v *= alpha;
                else if (epi == 1) v -= 0.5f * raux;
                else if (epi == 2) v = v / (raux + EPS_);
                else if (epi == 5) v -= 0.5f * aux[(long long)bz * auxStride + col];
                else if (epi == 3) { v += bias[col]; v = v > 0.f ? v : 0.f; }
                else if (epi == 4) v += bias[col];
                if (obf) ((ushort_t*)Cp)[off] = f2bf(v);
                else     ((float*)Cp)[off] = v;
            }
        }
    }
}

// seed C rows with bias[col] (bias!=null) or zero, ldc = 1024
__global__ __launch_bounds__(256)
void seed_c(const float* __restrict__ bias, float* __restrict__ C)
{
    const long long t = (long long)blockIdx.x * 256 + threadIdx.x;
    C[t] = bias ? bias[(int)(t & (D2_ - 1))] : 0.f;
}

// ---------- build / convert kernels ----------------------------------------

// 1024x1024 fp32 W -> bf16 W^T  (out[n][k] = W[k][n])
__global__ __launch_bounds__(256)
void transpose_cvt_sq(const float* __restrict__ W, ushort_t* __restrict__ out)
{
    __shared__ float S[32][33];
    const int tx = threadIdx.x & 31, ty = threadIdx.x >> 5;
    const int n0 = blockIdx.x * 32, k0 = blockIdx.y * 32;
    #pragma unroll
    for (int r = 0; r < 4; ++r)
        S[ty + 8 * r][tx] = W[(long long)(k0 + ty + 8 * r) * 1024 + n0 + tx];
    __syncthreads();
    #pragma unroll
    for (int r = 0; r < 4; ++r)
        out[(long long)(n0 + ty + 8 * r) * 1024 + k0 + tx] = f2bf(S[tx][ty + 8 * r]);
}

// wc1T (4096 x 1024): out[j][i] of combined [[W1r,W1i],[-W1i,W1r]]
__global__ __launch_bounds__(256)
void build_wc1T(const float* __restrict__ W1r, const float* __restrict__ W1i,
                ushort_t* __restrict__ out)
{
    __shared__ float S[32][33];
    const int tx = threadIdx.x & 31, ty = threadIdx.x >> 5;
    const int i0 = blockIdx.x * 32, j0 = blockIdx.y * 32;
    #pragma unroll
    for (int r = 0; r < 4; ++r) {
        const int i = i0 + ty + 8 * r, j = j0 + tx;
        float v;
        if (j < H_) v = (i < D_) ? W1r[(long long)i * H_ + j]
                                 : -W1i[(long long)(i - D_) * H_ + j];
        else {
            const int jj = j - H_;
            v = (i < D_) ? W1i[(long long)i * H_ + jj]
                         : W1r[(long long)(i - D_) * H_ + jj];
        }
        S[tx][ty + 8 * r] = v;
    }
    __syncthreads();
    #pragma unroll
    for (int r = 0; r < 4; ++r)
        out[(long long)(j0 + ty + 8 * r) * 1024 + i0 + tx] = f2bf(S[ty + 8 * r][tx]);
}

// wc2T (1024 x 4096): out[j][i] of combined [[W2r,W2i],[-W2i,W2r]]
__global__ __launch_bounds__(256)
void build_wc2T(const float* __restrict__ W2r, const float* __restrict__ W2i,
                ushort_t* __restrict__ out)
{
    __shared__ float S[32][33];
    const int tx = threadIdx.x & 31, ty = threadIdx.x >> 5;
    const int i0 = blockIdx.x * 32, j0 = blockIdx.y * 32;
    #pragma unroll
    for (int r = 0; r < 4; ++r) {
        const int i = i0 + ty + 8 * r, j = j0 + tx;
        float v;
        if (i < H_) v = (j < D_) ? W2r[(long long)i * D_ + j]
                                 : W2i[(long long)i * D_ + (j - D_)];
        else {
            const int ii = i - H_;
            v = (j < D_) ? -W2i[(long long)ii * D_ + j]
                         : W2r[(long long)ii * D_ + (j - D_)];
        }
        S[tx][ty + 8 * r] = v;
    }
    __syncthreads();
    #pragma unroll
    for (int r = 0; r < 4; ++r)
        out[(long long)(j0 + ty + 8 * r) * 4096 + i0 + tx] = f2bf(S[ty + 8 * r][tx]);
}

__global__ __launch_bounds__(256)
void build_bias(const float* __restrict__ b1r, const float* __restrict__ b1i,
                const float* __restrict__ b2r, const float* __restrict__ b2i,
                float* __restrict__ bc1, float* __restrict__ bc2)
{
    const int t = blockIdx.x * 256 + threadIdx.x;   // grid 16 -> t < 4096
    bc1[t] = (t < H_) ? b1r[t] : b1i[t - H_];
    if (t < D2_) bc2[t] = (t < D_) ? b2r[t] : b2i[t - D_];
}

__global__ __launch_bounds__(256)
void cvt_Wf(const float* __restrict__ Wf, ushort_t* __restrict__ out)
{
    const int t = blockIdx.x * 256 + threadIdx.x;   // 262144
    out[t] = f2bf(Wf[t]);
}

// x_bf (N x D2) = bf16(concat(zr, zi))
__global__ __launch_bounds__(256)
void cvt_x(const float* __restrict__ zr, const float* __restrict__ zi,
           ushort_t* __restrict__ x)
{
    long long t = (long long)blockIdx.x * 256 + threadIdx.x;  // N*D2/4
    long long n = t >> 8;
    int j4 = (int)(t & 255) << 2;
    float4 v;
    if (j4 < D_) v = *(const float4*)(zr + n * D_ + j4);
    else         v = *(const float4*)(zi + n * D_ + (j4 - D_));
    uint2 o;
    o.x = (uint_t)f2bf(v.x) | ((uint_t)f2bf(v.y) << 16);
    o.y = (uint_t)f2bf(v.z) | ((uint_t)f2bf(v.w) << 16);
    *(uint2*)(x + n * D2_ + j4) = o;
}

// ssq[n] = sum_k bf2f(A[n,k])^2, row len 1024, one wave per row
// (k-side only: phi_k uses a GLOBAL max so the row-shift matters; the q-side
//  row-shift cancels under per-row max-subtraction and is not computed.)
__global__ __launch_bounds__(256)
void rowsumsq_bf(const ushort_t* __restrict__ A, float* __restrict__ out)
{
    const int wid = threadIdx.x >> 6, lane = threadIdx.x & 63;
    const long long row = (long long)blockIdx.x * 4 + wid;
    const ushort_t* a = A + row * D2_;
    float s = 0.f;
    #pragma unroll
    for (int h = 0; h < 2; ++h) {
        uint4 u = *(const uint4*)(a + h * 512 + lane * 8);
        const uint_t w[4] = {u.x, u.y, u.z, u.w};
        #pragma unroll
        for (int p = 0; p < 4; ++p) {
            float lo = bf2f((ushort_t)(w[p] & 0xffff));
            float hi = bf2f((ushort_t)(w[p] >> 16));
            s += lo * lo + hi * hi;
        }
    }
    #pragma unroll
    for (int off = 32; off; off >>= 1) s += __shfl_down(s, off, 64);
    if (lane == 0) out[row] = s;
}

// phi_q: per-row max-subtract + exp over M=256, pq fp32 -> bf16 out
__global__ __launch_bounds__(256)
void phi_rowmax_exp(const float* __restrict__ P, ushort_t* __restrict__ out)
{
    const long long row = blockIdx.x;
    const int t = threadIdx.x;
    const float v = P[row * M_ + t];
    float m = v;
    #pragma unroll
    for (int off = 32; off; off >>= 1) m = fmaxf(m, __shfl_down(m, off, 64));
    __shared__ float sm[4];
    const int wid = t >> 6, lane = t & 63;
    if (lane == 0) sm[wid] = m;
    __syncthreads();
    const float mm = fmaxf(fmaxf(sm[0], sm[1]), fmaxf(sm[2], sm[3]));
    out[row * M_ + t] = f2bf(expf(v - mm) * 0.0625f);
}

__global__ __launch_bounds__(256)
void gmax1(const float* __restrict__ P, float* __restrict__ part, int n)
{
    float m = -3.4e38f;
    for (long long i = (long long)blockIdx.x * 256 + threadIdx.x; i < n;
         i += (long long)gridDim.x * 256)
        m = fmaxf(m, P[i]);
    #pragma unroll
    for (int off = 32; off; off >>= 1) m = fmaxf(m, __shfl_down(m, off, 64));
    __shared__ float sm[4];
    const int wid = threadIdx.x >> 6, lane = threadIdx.x & 63;
    if (lane == 0) sm[wid] = m;
    __syncthreads();
    if (threadIdx.x == 0)
        part[blockIdx.x] = fmaxf(fmaxf(sm[0], sm[1]), fmaxf(sm[2], sm[3]));
}

__global__ __launch_bounds__(256)
void gmax2(float* __restrict__ red)
{
    float m = -3.4e38f;
    for (int i = threadIdx.x; i < 1024; i += 256) m = fmaxf(m, red[256 + i]);
    #pragma unroll
    for (int off = 32; off; off >>= 1) m = fmaxf(m, __shfl_down(m, off, 64));
    __shared__ float sm[4];
    const int wid = threadIdx.x >> 6, lane = threadIdx.x & 63;
    if (lane == 0) sm[wid] = m;
    __syncthreads();
    if (threadIdx.x == 0) red[0] = fmaxf(fmaxf(sm[0], sm[1]), fmaxf(sm[2], sm[3]));
}

// phi_kT = bf16(exp(pkT - gmax)/16)
__global__ __launch_bounds__(256)
void phikT_exp(const float* __restrict__ P, const float* __restrict__ red,
               ushort_t* __restrict__ out)
{
    const long long i = (long long)blockIdx.x * 256 + threadIdx.x;
    out[i] = f2bf(expf(P[i] - red[0]) * 0.0625f);
}

// ksum[b,m] = sum_l phi_kT[m, b*L+l]; one block per (b,m)
__global__ __launch_bounds__(256)
void ksum_k(const ushort_t* __restrict__ phikT, float* __restrict__ ks)
{
    const int b = blockIdx.x >> 8, m = blockIdx.x & 255;
    const ushort_t* p = phikT + (long long)m * N_ + b * L_;
    uint4 u = *(const uint4*)(p + threadIdx.x * 8);
    const uint_t w[4] = {u.x, u.y, u.z, u.w};
    float s = 0.f;
    #pragma unroll
    for (int q = 0; q < 4; ++q)
        s += bf2f((ushort_t)(w[q] & 0xffff)) + bf2f((ushort_t)(w[q] >> 16));
    #pragma unroll
    for (int off = 32; off; off >>= 1) s += __shfl_down(s, off, 64);
    __shared__ float sm[4];
    const int wid = threadIdx.x >> 6, lane = threadIdx.x & 63;
    if (lane == 0) sm[wid] = s;
    __syncthreads();
    if (threadIdx.x == 0)
        ks[blockIdx.x] = sm[0] + sm[1] + sm[2] + sm[3];
}

// den[n] = sum_m phi_q_bf[n,m]*ksum[b,m]; one wave per row
__global__ __launch_bounds__(256)
void den_k(const ushort_t* __restrict__ phiq, const float* __restrict__ ks,
           float* __restrict__ den)
{
    const int wid = threadIdx.x >> 6, lane = threadIdx.x & 63;
    const long long n = (long long)blockIdx.x * 4 + wid;
    const int b = (int)(n >> 11);
    uint2 u = *(const uint2*)(phiq + n * M_ + lane * 4);
    float4 kk = *(const float4*)(ks + b * M_ + lane * 4);
    float s = bf2f((ushort_t)(u.x & 0xffff)) * kk.x
            + bf2f((ushort_t)(u.x >> 16)) * kk.y
            + bf2f((ushort_t)(u.y & 0xffff)) * kk.z
            + bf2f((ushort_t)(u.y >> 16)) * kk.w;
    #pragma unroll
    for (int off = 32; off; off >>= 1) s += __shfl_down(s, off, 64);
    if (lane == 0) den[n] = s;
}

// zst_bf = bf16(modrelu(z + yo)); yo is bf16 (N x D2), full-N launch
__global__ __launch_bounds__(256)
void modrelu_attn(const float* __restrict__ zr, const float* __restrict__ zi,
                  const ushort_t* __restrict__ yo, const float* __restrict__ b_attn,
                  ushort_t* __restrict__ zst)
{
    const long long t = (long long)blockIdx.x * 256 + threadIdx.x;
    const long long n = t >> 9; const int d = (int)(t & 511);
    const float ar = zr[t] + bf2f(yo[n * D2_ + d]);
    const float ai = zi[t] + bf2f(yo[n * D2_ + D_ + d]);
    const float mag = sqrtf(ar * ar + ai * ai + EPS_);
    const float s = fmaxf(mag + b_attn[d], 0.f) / mag;
    zst[n * D2_ + d]      = f2bf(ar * s);
    zst[n * D2_ + D_ + d] = f2bf(ai * s);
}

// out chunk = modrelu(zst + f) interleaved; zst(bf16)/f/out pre-offset
__global__ __launch_bounds__(256)
void modrelu_out(const ushort_t* __restrict__ zst, const float* __restrict__ f,
                 const float* __restrict__ b_ffn, float* __restrict__ out)
{
    const long long t = (long long)blockIdx.x * 256 + threadIdx.x;
    const long long n = t >> 9; const int d = (int)(t & 511);
    const float ar = bf2f(zst[n * D2_ + d])      + f[n * D2_ + d];
    const float ai = bf2f(zst[n * D2_ + D_ + d]) + f[n * D2_ + D_ + d];
    const float mag = sqrtf(ar * ar + ai * ai + EPS_);
    const float s = fmaxf(mag + b_ffn[d], 0.f) / mag;
    out[t * 2]     = ar * s;
    out[t * 2 + 1] = ai * s;
}

extern "C" void kernel_launch(void* const* d_in, const int* in_sizes, int n_in,
                              void* d_out, int out_size, void* d_ws, size_t ws_size,
                              hipStream_t stream)
{
    const float* zr    = (const float*)d_in[0];
    const float* zi    = (const float*)d_in[1];
    const float* Wq    = (const float*)d_in[2];
    const float* Wk    = (const float*)d_in[3];
    const float* Wv    = (const float*)d_in[4];
    const float* Wo    = (const float*)d_in[5];
    const float* Wf    = (const float*)d_in[6];
    const float* b_attn= (const float*)d_in[7];
    const float* W1r   = (const float*)d_in[8];
    const float* W1i   = (const float*)d_in[9];
    const float* b1r   = (const float*)d_in[10];
    const float* b1i   = (const float*)d_in[11];
    const float* W2r   = (const float*)d_in[12];
    const float* W2i   = (const float*)d_in[13];
    const float* b2r   = (const float*)d_in[14];
    const float* b2i   = (const float*)d_in[15];
    const float* b_ffn = (const float*)d_in[16];

    char* w = (char*)d_ws;
    // Attention-phase layout (~124 MB):
    ushort_t* Xbf = (ushort_t*)(w + 0LL);          // x_bf -> zst_bf (33.55 MB)
    ushort_t* A1  = (ushort_t*)(w + 33554432LL);   // q/k -> vT (33.55 MB)
    float*    P   = (float*)   (w + 67108864LL);   // pq/pkT -> yo_bf16 (16.8)
    ushort_t* WqT = (ushort_t*)(w + 83886080LL);   // after P (dead then)
    ushort_t* WkT = (ushort_t*)(w + 85983232LL);
    ushort_t* WvT = (ushort_t*)(w + 88080384LL);
    ushort_t* Wfb = (ushort_t*)(w + 90177536LL);
    ushort_t* F1  = (ushort_t*)(w + 100663296LL);  // phi_q_bf -> wc1T (8.39 MB)
    ushort_t* F2  = (ushort_t*)(w + 109051904LL);  // phi_kT -> G -> wc2T (8.39)
    ushort_t* WoT = (ushort_t*)(w + 117440512LL);  // 2 MB
    ushort_t* KVT = (ushort_t*)(w + 119537664LL);  // KVT' (8,256,1024) bf16, 4MB
    float* ssqk = (float*)(w + 123797504LL);
    float* den  = (float*)(w + 123863040LL);
    float* ksum = (float*)(w + 123928576LL);
    float* red  = (float*)(w + 123936768LL);

    // FFN-phase layout, gated on ws_size:
    const bool big = ws_size >= 152000000ULL;
    const int  RCH = big ? 8192 : 4096;
    ushort_t* Hb = (ushort_t*)(w + 33554432LL);
    float* Fb  = big ? (float*)(w + 117440512LL) : (float*)(w + 67108864LL);
    float* bc1 = big ? (float*)(w + 150994944LL) : (float*)(w + 123944960LL);
    float* bc2 = big ? (float*)(w + 151011328LL) : (float*)(w + 123961344LL);

    const float scl = 0.1767766952966369f;  // D2^-0.25
    dim3 blk(256);

    // Route: 256x256 16-wave kernel when the grid is wide enough (>=128 wgs)
    // and dims allow; else the 128x128 2-buffer kernel.
    auto GM = [&](const ushort_t* A, const ushort_t* Bm, void* C,
                  int rows, int cols, int K, int lda, int ldb, int ldc,
                  long long sA, long long sB, long long sC, int nb,
                  int epi, float alpha, const float* aux, int auxStride,
                  const float* bias, int obf) {
        const long long wg256 = (long long)(cols >> 8) * (rows >> 8) * nb;
        if ((rows & 255) == 0 && (cols & 255) == 0 && (K & 127) == 0 &&
            wg256 >= 128) {
            dim3 grid(cols / 256, rows / 256, nb);
            gemm256<<<grid, dim3(1024), 0, stream>>>(A, Bm, C, K, lda, ldb, ldc,
                                                     sA, sB, sC, epi, alpha, aux,
                                                     auxStride, bias, obf, 1);
        } else {
            dim3 grid(cols / 128, rows / 128, nb);
            gemm_mfma<<<grid, blk, 0, stream>>>(A, Bm, C, K, lda, ldb, ldc,
                                                sA, sB, sC, epi, alpha, aux,
                                                auxStride, bias, obf);
        }
    };

    // ---- one-time weight prep + input convert ----
    transpose_cvt_sq<<<dim3(32, 32), blk, 0, stream>>>(Wq, WqT);
    transpose_cvt_sq<<<dim3(32, 32), blk, 0, stream>>>(Wk, WkT);
    transpose_cvt_sq<<<dim3(32, 32), blk, 0, stream>>>(Wv, WvT);
    transpose_cvt_sq<<<dim3(32, 32), blk, 0, stream>>>(Wo, WoT);
    cvt_Wf<<<1024, blk, 0, stream>>>(Wf, Wfb);
    build_bias<<<16, blk, 0, stream>>>(b1r, b1i, b2r, b2i, bc1, bc2);
    cvt_x<<<N_ * (D2_ / 4) / 256, blk, 0, stream>>>(zr, zi, Xbf);

    // ---- q phase: q_bf = x@WqT*scl; pq = q@Wf^T (the -0.5*ssqq row-shift
    //      cancels under per-row max-subtraction -- not computed); phi_q ----
    GM(Xbf, WqT, A1, N_, D2_, D2_, D2_, D2_, D2_, 0, 0, 0, 1, 0, scl, nullptr, 0, nullptr, 1);
    GM(A1, Wfb, P, N_, M_, D2_, D2_, D2_, M_, 0, 0, 0, 1, 0, 1.f, nullptr, 0, nullptr, 0);
    phi_rowmax_exp<<<N_, blk, 0, stream>>>(P, F1);

    // ---- k phase: k_bf; ssqk; pkT = Wf@k^T - 0.5ssqk[col]; phi_kT ----
    GM(Xbf, WkT, A1, N_, D2_, D2_, D2_, D2_, D2_, 0, 0, 0, 1, 0, scl, nullptr, 0, nullptr, 1);
    rowsumsq_bf<<<N_ / 4, blk, 0, stream>>>(A1, ssqk);
    GM(Wfb, A1, P, M_, N_, D2_, D2_, D2_, N_, 0, 0, 0, 1, 5, 1.f, ssqk, 0, nullptr, 0);
    gmax1<<<1024, blk, 0, stream>>>(P, red + 256, M_ * N_);
    gmax2<<<1, blk, 0, stream>>>(red);
    phikT_exp<<<M_ * N_ / 256, blk, 0, stream>>>(P, red, F2);

    // ---- vT = Wv^T @ x^T (1024 x 16384) ----
    GM(WvT, Xbf, A1, D2_, N_, D2_, D2_, D2_, N_, 0, 0, 0, 1, 0, 1.f, nullptr, 0, nullptr, 1);

    // ---- ksum (before F2 region is reused); KVT'[b][m][d] = sum_l
    //      phi_kT[m][bL+l] * vT[d][bL+l]  (256 x 1024 per batch) ----
    ksum_k<<<B_ * M_, blk, 0, stream>>>(F2, ksum);
    GM(F2, A1, KVT, M_, D2_, L_, N_, N_, D2_, L_, L_, (long long)M_ * D2_, B_,
       0, 1.f, nullptr, 0, nullptr, 1);

    // ---- Wo folding: G[b][o][m] = sum_d WoT[o][d] * KVT'[b][m][d]
    //      (1024 x 256 per batch, ldc=256, into F2 region -- phi_kT dead) ----
    ushort_t* Gb = F2;
    GM(WoT, KVT, Gb, D2_, M_, D2_, D2_, D2_, M_,
       0, (long long)M_ * D2_, (long long)D2_ * M_, B_,
       0, 1.f, nullptr, 0, nullptr, 1);

    // ---- den; yo_bf[b][n][o] = (sum_m phi_q[n][m]*G[b][o][m])/(den+eps)
    //      bf16 out into P region ----
    den_k<<<N_ / 4, blk, 0, stream>>>(F1, ksum, den);
    GM(F1, Gb, P, L_, D2_, M_, M_, M_, D2_, (long long)L_ * M_,
       (long long)D2_ * M_, (long long)L_ * D2_, B_, 2, 1.f, den, L_, nullptr, 1);

    // ---- attn modrelu over full N (yo read as bf16) ----
    modrelu_attn<<<N_ * D_ / 256, blk, 0, stream>>>(
        zr, zi, (const ushort_t*)P, b_attn, Xbf);

    // ---- combined FFN weights into F1/F2 (phi/G buffers dead) ----
    build_wc1T<<<dim3(32, 128), blk, 0, stream>>>(W1r, W1i, F1);
    build_wc2T<<<dim3(128, 32), blk, 0, stream>>>(W2r, W2i, F2);

    // ---- FFN + final modrelu, N_/RCH chunks ----
    // FFN2 (rows x 1024, K=4096) only fills 128 wgs at 256^2 -> split-K=2:
    // seed Fb with bias, both K-halves atomicAdd (grid 4 x rows/256 x 2).
    for (int c = 0; c < N_ / RCH; ++c) {
        const long long ro = (long long)c * RCH;
        GM(Xbf + ro * D2_, F1, Hb, RCH, 2 * H_, D2_, D2_, D2_, 2 * H_,
           0, 0, 0, 1, 3, 1.f, nullptr, 0, bc1, 1);
        if (RCH == 8192) {
            seed_c<<<RCH * D2_ / 256, blk, 0, stream>>>(bc2, Fb);
            dim3 grid2(D2_ / 256, RCH / 256, 2);
            gemm256<<<grid2, dim3(1024), 0, stream>>>(
                Hb, F2, Fb, 2 * H_, 2 * H_, 2 * H_, D2_,
                0, 0, 0, 4, 1.f, nullptr, 0, bc2, 0, 2);
        } else {
            GM(Hb, F2, Fb, RCH, D2_, 2 * H_, 2 * H_, 2 * H_, D2_,
               0, 0, 0, 1, 4, 1.f, nullptr, 0, bc2, 0);
        }
        modrelu_out<<<RCH * D_ / 256, blk, 0, stream>>>(
            Xbf + ro * D2_, Fb, b_ffn, (float*)d_out + ro * D2_);
    }

    (void)in_sizes; (void)n_in; (void)out_size;
}